// Round 8
// baseline (385.509 us; speedup 1.0000x reference)
//
#include <hip/hip_runtime.h>
#include <cstddef>
#include <cstdint>

#define NB 8
#define NQ 4096

typedef __attribute__((ext_vector_type(8))) short bfrag8;
typedef __attribute__((ext_vector_type(4))) float facc4;
typedef __attribute__((ext_vector_type(4))) unsigned short us4;
typedef __attribute__((ext_vector_type(8))) unsigned short us8;

__device__ __forceinline__ float bf2f(unsigned short u) {
  union { unsigned int i; float f; } v; v.i = ((unsigned int)u) << 16; return v.f;
}
__device__ __forceinline__ unsigned short f2bf(float f) {
  union { float f; unsigned int i; } v; v.f = f;
  unsigned int r = v.i + 0x7FFFu + ((v.i >> 16) & 1u);
  return (unsigned short)(r >> 16);
}
__device__ __forceinline__ void gload16(const void* g, void* l) {
  __builtin_amdgcn_global_load_lds(
      (const __attribute__((address_space(1))) void*)g,
      (__attribute__((address_space(3))) void*)l, 16, 0, 0);
}

// ================= mega prep: embarrassingly-parallel weight conversions =================
struct PrepArgs {
  const float *gc_w, *up_w, *up_b;
  const float *so_w0, *so_b0, *so_w1, *so_b1;
  const float *aw_w0, *aw_b0, *aw_w1, *aw_b1;
  const float *op_w0, *op_w1;
  unsigned short *PET, *WG, *WUP, *OPT0, *OPT1, *SOW0, *SOW1;
  float *BUPP, *SOB0, *SOB1;
};

__global__ __launch_bounds__(256) void mega_prep(PrepArgs p) {
  const int blk = blockIdx.x, t = threadIdx.x;
  if (blk < 4096) {
    int idx = blk * 256 + t;
    int q = idx >> 8, c = idx & 255;
    int h = q >> 6, w = q & 63;
    int k = c >> 2, m = c & 3;
    float dv = expf((float)(2 * k) * (-9.210340371976184f / 128.0f));
    float arg = ((m < 2) ? (float)w : (float)h) * dv;
    p.PET[idx] = f2bf(((m & 1) == 0) ? sinf(arg) : cosf(arg));
  } else if (blk < 5120) {
    int i = (blk - 4096) * 256 + t;
    p.WG[i] = f2bf(p.gc_w[i]);
  } else if (blk < 5504) {
    int i = (blk - 5120) * 256 + t;
    int m = i >> 8, k = i & 255;
    p.WUP[i] = (m < 320) ? f2bf(p.up_w[m * 256 + k]) : 0;
  } else if (blk < 5505) {
    p.BUPP[t] = (t < 320) ? p.up_b[t] : 0.f;
    if (t < 128) {
      int i2 = 256 + t;
      p.BUPP[i2] = (i2 < 320) ? p.up_b[i2] : 0.f;
    }
  } else if (blk < 6017) {
    int i = (blk - 5505) * 256 + t;
    int which = i >> 16, j = i & 65535;
    int o = j >> 8, k = j & 255;
    (which ? p.OPT1 : p.OPT0)[j] = f2bf((which ? p.op_w1 : p.op_w0)[k * 256 + o]);
  } else {
    int i = (blk - 6017) * 256 + t;
    int which = i >> 15, j = i & 32767;
    int row = j >> 8, k = j & 255;
    const float* sw = which ? p.so_w1 : p.so_w0;
    const float* aw = which ? p.aw_w1 : p.aw_w0;
    float v = 0.f;
    if (row < 64) v = sw[k * 64 + row];
    else if (row < 96) v = aw[k * 32 + (row - 64)];
    (which ? p.SOW1 : p.SOW0)[j] = f2bf(v);
    if (j < 128) {
      const float* sb = which ? p.so_b1 : p.so_b0;
      const float* ab = which ? p.aw_b1 : p.aw_b0;
      (which ? p.SOB1 : p.SOB0)[j] = (j < 64) ? sb[j] : ((j < 96) ? ab[j - 64] : 0.f);
    }
  }
}

// ================= WV/BV: tiled LDS-staged small GEMM =================
__global__ __launch_bounds__(256) void k_wv(const float* __restrict__ vp_w0,
                                            const float* __restrict__ vp_b0,
                                            const float* __restrict__ vp_w1,
                                            const float* __restrict__ vp_b1,
                                            const float* __restrict__ sc_w,
                                            const float* __restrict__ sc_b,
                                            unsigned short* __restrict__ WV0,
                                            unsigned short* __restrict__ WV1,
                                            float* __restrict__ BV0,
                                            float* __restrict__ BV1) {
  const int br = blockIdx.y, kt = blockIdx.x, k0 = kt * 20, t = threadIdx.x;
  const float* vp = br ? vp_w1 : vp_w0;
  unsigned short* WV = br ? WV1 : WV0;
  __shared__ float vt[32][256];
  __shared__ float st[32][20];
  __shared__ float sb[32];
  float acc[20] = {};
  float accB = 0.f;
  for (int c0 = 0; c0 < 256; c0 += 32) {
    __syncthreads();
#pragma unroll
    for (int cc = 0; cc < 32; ++cc)
      vt[cc][t] = vp[(size_t)(c0 + cc) * 256 + t];
    for (int i = t; i < 640; i += 256)
      st[i / 20][i % 20] = sc_w[(size_t)(c0 + i / 20) * 320 + k0 + (i % 20)];
    if (t < 32) sb[t] = sc_b[c0 + t];
    __syncthreads();
#pragma unroll
    for (int cc = 0; cc < 32; ++cc) {
      float v = vt[cc][t];
      accB = fmaf(v, sb[cc], accB);
#pragma unroll
      for (int j = 0; j < 20; ++j)
        acc[j] = fmaf(v, st[cc][j], acc[j]);
    }
  }
#pragma unroll
  for (int j = 0; j < 20; ++j) WV[(size_t)t * 320 + k0 + j] = f2bf(acc[j]);
  if (kt == 0) (br ? BV1 : BV0)[t] = (br ? vp_b1 : vp_b0)[t] + accB;
}

// ================= 128x128 GEMM (PESO / SW dispatches) =================
struct GArgs {
  const unsigned short* W[2];
  const unsigned short* X[2];
  const float* bias[2];
  void* out[2];
  const unsigned short* res[2];
  float rscale[2];
  int K, ldm, bmask, brshift;
};
// MODE 1: out = rscale*acc + bias ; MODE 2: out = acc + rscale*res[n*128+m]
template <int MODE>
__global__ __launch_bounds__(256) void gemm_bf16(GArgs g) {
  __shared__ unsigned short As[8192];
  __shared__ unsigned short Bs[8192];
  const int t = threadIdx.x;
  const int lane = t & 63, w = t >> 6;
  const int z = blockIdx.z;
  const int b = z & g.bmask, br = z >> g.brshift;
  const int K = g.K;
  const int n0 = blockIdx.x * 128;
  const unsigned short* W = g.W[br];
  const unsigned short* Xb = g.X[br] + (size_t)b * NQ * K;

  const unsigned short* asrc[4];
  const unsigned short* bsrc[4];
  unsigned short* adst[4];
  unsigned short* bdst[4];
#pragma unroll
  for (int i = 0; i < 4; ++i) {
    int cid = i * 256 + t;
    int row = cid >> 3;
    int cc = (cid & 7) ^ (row & 7);
    asrc[i] = W + (size_t)row * K + cc * 8;
    bsrc[i] = Xb + (size_t)(n0 + row) * K + cc * 8;
    adst[i] = &As[i * 2048 + w * 512];
    bdst[i] = &Bs[i * 2048 + w * 512];
  }
  const int wm = (w >> 1) * 64, wn = (w & 1) * 64;
  const int l15 = lane & 15, l4 = lane >> 4;
  facc4 acc[4][4];
#pragma unroll
  for (int i = 0; i < 4; ++i)
#pragma unroll
    for (int j = 0; j < 4; ++j) acc[i][j] = facc4{0.f, 0.f, 0.f, 0.f};

  for (int k0 = 0; k0 < K; k0 += 64) {
    if (k0) __syncthreads();
#pragma unroll
    for (int i = 0; i < 4; ++i) {
      gload16(asrc[i], adst[i]);
      gload16(bsrc[i], bdst[i]);
      asrc[i] += 64; bsrc[i] += 64;
    }
    __syncthreads();
#pragma unroll
    for (int kk = 0; kk < 2; ++kk) {
      bfrag8 af[4], bf[4];
#pragma unroll
      for (int mi = 0; mi < 4; ++mi) {
        int row = wm + mi * 16 + l15;
        af[mi] = *reinterpret_cast<const bfrag8*>(&As[row * 64 + (((kk * 4 + l4) ^ (row & 7)) * 8)]);
      }
#pragma unroll
      for (int ni = 0; ni < 4; ++ni) {
        int row = wn + ni * 16 + l15;
        bf[ni] = *reinterpret_cast<const bfrag8*>(&Bs[row * 64 + (((kk * 4 + l4) ^ (row & 7)) * 8)]);
      }
#pragma unroll
      for (int mi = 0; mi < 4; ++mi)
#pragma unroll
        for (int ni = 0; ni < 4; ++ni)
          acc[mi][ni] = __builtin_amdgcn_mfma_f32_16x16x32_bf16(af[mi], bf[ni], acc[mi][ni], 0, 0, 0);
    }
  }
  const size_t bq = (size_t)b * NQ;
#pragma unroll
  for (int mi = 0; mi < 4; ++mi) {
#pragma unroll
    for (int ni = 0; ni < 4; ++ni) {
      int m = wm + mi * 16 + l4 * 4;
      int n = n0 + wn + ni * 16 + l15;
      facc4 v = acc[mi][ni];
      unsigned short* o16 = (unsigned short*)g.out[br];
      float rv[4] = {v[0], v[1], v[2], v[3]};
      if constexpr (MODE == 1) {
        float sc = g.rscale[br];
        float4 bv = *reinterpret_cast<const float4*>(&g.bias[br][m]);
        rv[0] = rv[0] * sc + bv.x; rv[1] = rv[1] * sc + bv.y;
        rv[2] = rv[2] * sc + bv.z; rv[3] = rv[3] * sc + bv.w;
      }
      if constexpr (MODE == 2) {
        float sc = g.rscale[br];
        us4 rr = *reinterpret_cast<const us4*>(&g.res[br][(size_t)n * 128 + m]);
#pragma unroll
        for (int r = 0; r < 4; ++r) rv[r] += sc * bf2f(rr[r]);
      }
      us4 pk;
#pragma unroll
      for (int r = 0; r < 4; ++r) pk[r] = f2bf(rv[r]);
      *reinterpret_cast<us4*>(&o16[(bq + n) * g.ldm + m]) = pk;
    }
  }
}

// ================= N=64 full-M GEMM with fused f32 transpose (gconv / VP) =================
struct NArgs {
  const unsigned short* W[2];
  const void* X[2];
  const float* bias[2];
  void* out[2];
  int K, zmask, zshift;
};
__global__ __launch_bounds__(256) void gemm_n64(NArgs g) {
  __shared__ unsigned short As[16384]; // [256][64] swizzled
  __shared__ unsigned short Bs[4096];  // [64][64] swizzled
  const int t = threadIdx.x;
  const int lane = t & 63, w = t >> 6;
  const int z = blockIdx.z;
  const int b = z & g.zmask, br = z >> g.zshift;
  const int K = g.K;
  const int n0 = blockIdx.x * 64;

  const unsigned short* W = g.W[br];
  const unsigned short* asrc[8];
  unsigned short* adst[8];
#pragma unroll
  for (int i = 0; i < 8; ++i) {
    int c = t + 256 * i;
    int row = c >> 3;
    int k8 = (c & 7) ^ (row & 7);
    asrc[i] = W + (size_t)row * K + k8 * 8;
    adst[i] = &As[w * 512 + i * 2048];
  }

  const int kb = t >> 4, nb = t & 15;
  const float* Xf = (const float*)g.X[br];
  const float* bsrcf = Xf + (size_t)b * K * NQ + (size_t)(kb * 4) * NQ + n0 + nb * 4;

  const int l15 = lane & 15, l4 = lane >> 4;
  facc4 acc[4][4];
#pragma unroll
  for (int i = 0; i < 4; ++i)
#pragma unroll
    for (int j = 0; j < 4; ++j) acc[i][j] = facc4{0.f, 0.f, 0.f, 0.f};

  for (int k0 = 0; k0 < K; k0 += 64) {
    if (k0) __syncthreads();
#pragma unroll
    for (int i = 0; i < 8; ++i) {
      gload16(asrc[i], adst[i]);
      asrc[i] += 64;
    }
    {
      float vv[4][4];
#pragma unroll
      for (int r = 0; r < 4; ++r) {
        float4 v = *reinterpret_cast<const float4*>(bsrcf + (size_t)k0 * NQ + (size_t)r * NQ);
        vv[r][0] = v.x; vv[r][1] = v.y; vv[r][2] = v.z; vv[r][3] = v.w;
      }
#pragma unroll
      for (int c = 0; c < 4; ++c) {
        int n = nb * 4 + c;
        us4 pk;
        pk[0] = f2bf(vv[0][c]); pk[1] = f2bf(vv[1][c]);
        pk[2] = f2bf(vv[2][c]); pk[3] = f2bf(vv[3][c]);
        int off = n * 64 + (((kb >> 1) ^ (n & 7)) * 8) + (kb & 1) * 4;
        *reinterpret_cast<us4*>(&Bs[off]) = pk;
      }
    }
    __syncthreads();
#pragma unroll
    for (int kk = 0; kk < 2; ++kk) {
      bfrag8 af[4], bf[4];
#pragma unroll
      for (int mi = 0; mi < 4; ++mi) {
        int row = w * 64 + mi * 16 + l15;
        af[mi] = *reinterpret_cast<const bfrag8*>(&As[row * 64 + (((kk * 4 + l4) ^ (row & 7)) * 8)]);
      }
#pragma unroll
      for (int ni = 0; ni < 4; ++ni) {
        int row = ni * 16 + l15;
        bf[ni] = *reinterpret_cast<const bfrag8*>(&Bs[row * 64 + (((kk * 4 + l4) ^ (row & 7)) * 8)]);
      }
#pragma unroll
      for (int mi = 0; mi < 4; ++mi)
#pragma unroll
        for (int ni = 0; ni < 4; ++ni)
          acc[mi][ni] = __builtin_amdgcn_mfma_f32_16x16x32_bf16(af[mi], bf[ni], acc[mi][ni], 0, 0, 0);
    }
  }

  const size_t bq = (size_t)b * NQ;
  unsigned short* o16 = (unsigned short*)g.out[br];
#pragma unroll
  for (int mi = 0; mi < 4; ++mi) {
#pragma unroll
    for (int ni = 0; ni < 4; ++ni) {
      int m = w * 64 + mi * 16 + l4 * 4;
      int n = n0 + ni * 16 + l15;
      facc4 v = acc[mi][ni];
      float4 bv = *reinterpret_cast<const float4*>(&g.bias[br][m]);
      us4 pk;
      pk[0] = f2bf(v[0] + bv.x); pk[1] = f2bf(v[1] + bv.y);
      pk[2] = f2bf(v[2] + bv.z); pk[3] = f2bf(v[3] + bv.w);
      *reinterpret_cast<us4*>(&o16[(bq + n) * 256 + m]) = pk;
    }
  }
}

// ================= fused tail: gather + dual op-proj + blend -> FUSED =================
struct TArgs {
  const unsigned short *VP0, *VP1, *SWb, *OPT0, *OPT1;
  const float *opb0, *opb1;
  const unsigned short *G, *PET;
  const float *afin;
  unsigned short *FUSED;
};

__global__ __launch_bounds__(256) void k_tail(TArgs g) {
  __shared__ unsigned short sws[8192];  // [64][128]
  __shared__ unsigned short P[16384];   // [4 kt][64 q][64 k] swizzled
  __shared__ unsigned short As[16384];  // [256][64] swizzled
  const int t = threadIdx.x;
  const int lane = t & 63, w = t >> 6;
  const int b = blockIdx.y;
  const int q0 = blockIdx.x * 64;
  const int l15 = lane & 15, l4 = lane >> 4;

  facc4 acc0[4][4], acc1[4][4];
#pragma unroll
  for (int i = 0; i < 4; ++i)
#pragma unroll
    for (int j = 0; j < 4; ++j) {
      acc0[i][j] = facc4{0.f, 0.f, 0.f, 0.f};
      acc1[i][j] = facc4{0.f, 0.f, 0.f, 0.f};
    }

  auto branch_pass = [&](int br, facc4 (&accR)[4][4]) {
    __syncthreads(); // protect sws/P overwrite vs previous reads
    const unsigned short* SWp = g.SWb + (((size_t)br * NB + b) * NQ + q0) * 128;
#pragma unroll
    for (int i = 0; i < 4; ++i) {
      int idx = (t + 256 * i) * 8;
      *reinterpret_cast<us8*>(&sws[idx]) = *reinterpret_cast<const us8*>(&SWp[idx]);
    }
    __syncthreads();
    const unsigned short* VP = (br ? g.VP1 : g.VP0) + (size_t)b * NQ * 256;
#pragma unroll
    for (int i = 0; i < 8; ++i) {
      int tau = t + 256 * i;
      int qi = tau >> 5, seg = tau & 31, head = seg >> 2, hdg = seg & 3;
      int q = q0 + qi;
      const unsigned short* sw = &sws[qi * 128];
      float l0 = bf2f(sw[64 + head * 4 + 0]);
      float l1 = bf2f(sw[64 + head * 4 + 1]);
      float l2 = bf2f(sw[64 + head * 4 + 2]);
      float l3 = bf2f(sw[64 + head * 4 + 3]);
      float mx = fmaxf(fmaxf(l0, l1), fmaxf(l2, l3));
      float e0 = expf(l0 - mx), e1 = expf(l1 - mx), e2 = expf(l2 - mx), e3 = expf(l3 - mx);
      float inv = 1.f / (e0 + e1 + e2 + e3);
      float aw[4] = {e0 * inv, e1 * inv, e2 * inv, e3 * inv};
      float rpx = (float)(q & 63) * (64.f / 63.f) - 0.5f;
      float rpy = (float)(q >> 6) * (64.f / 63.f) - 0.5f;
      const unsigned short* vb = VP + head * 32 + hdg * 8;
      float accg[8] = {};
#pragma unroll
      for (int p = 0; p < 4; ++p) {
        float px = rpx + bf2f(sw[head * 8 + p * 2 + 0]);
        float py = rpy + bf2f(sw[head * 8 + p * 2 + 1]);
        float fx = floorf(px), fy = floorf(py);
        int x0 = (int)fx, y0 = (int)fy;
        float wx = px - fx, wy = py - fy;
#pragma unroll
        for (int dy = 0; dy < 2; ++dy) {
#pragma unroll
          for (int dx = 0; dx < 2; ++dx) {
            int xi = x0 + dx, yi = y0 + dy;
            if (xi >= 0 && xi < 64 && yi >= 0 && yi < 64) {
              float wa = aw[p] * (dx ? wx : 1.f - wx) * (dy ? wy : 1.f - wy);
              bfrag8 v = *reinterpret_cast<const bfrag8*>(&vb[(size_t)(yi * 64 + xi) * 256]);
#pragma unroll
              for (int j = 0; j < 8; ++j) accg[j] = fmaf(wa, bf2f((unsigned short)v[j]), accg[j]);
            }
          }
        }
      }
      us8 o;
#pragma unroll
      for (int j = 0; j < 8; ++j) o[j] = f2bf(accg[j]);
      int kt = seg >> 3, k8 = seg & 7;
      *reinterpret_cast<us8*>(&P[kt * 4096 + qi * 64 + ((k8 ^ (qi & 7)) * 8)]) = o;
    }
    const unsigned short* OPT = br ? g.OPT1 : g.OPT0;
    for (int kt = 0; kt < 4; ++kt) {
      __syncthreads();
#pragma unroll
      for (int i = 0; i < 8; ++i) {
        int c = t + 256 * i;
        int row = c >> 3;
        int k8 = (c & 7) ^ (row & 7);
        gload16(OPT + (size_t)row * 256 + kt * 64 + k8 * 8, &As[w * 512 + i * 2048]);
      }
      __syncthreads();
#pragma unroll
      for (int kk = 0; kk < 2; ++kk) {
        bfrag8 af[4], bf[4];
#pragma unroll
        for (int mi = 0; mi < 4; ++mi) {
          int row = w * 64 + mi * 16 + l15;
          af[mi] = *reinterpret_cast<const bfrag8*>(&As[row * 64 + (((kk * 4 + l4) ^ (row & 7)) * 8)]);
        }
#pragma unroll
        for (int ni = 0; ni < 4; ++ni) {
          int row = ni * 16 + l15;
          bf[ni] = *reinterpret_cast<const bfrag8*>(&P[kt * 4096 + row * 64 + (((kk * 4 + l4) ^ (row & 7)) * 8)]);
        }
#pragma unroll
        for (int mi = 0; mi < 4; ++mi)
#pragma unroll
          for (int ni = 0; ni < 4; ++ni)
            accR[mi][ni] = __builtin_amdgcn_mfma_f32_16x16x32_bf16(af[mi], bf[ni], accR[mi][ni], 0, 0, 0);
      }
    }
  };
  branch_pass(0, acc0);
  branch_pass(1, acc1);

  float a = g.afin[b];
  const size_t bq = (size_t)b * NQ;
#pragma unroll
  for (int mi = 0; mi < 4; ++mi) {
#pragma unroll
    for (int ni = 0; ni < 4; ++ni) {
      int m = w * 64 + mi * 16 + l4 * 4;
      int n = q0 + ni * 16 + l15;
      float4 b0 = *reinterpret_cast<const float4*>(&g.opb0[m]);
      float4 b1 = *reinterpret_cast<const float4*>(&g.opb1[m]);
      us4 gv = *reinterpret_cast<const us4*>(&g.G[(bq + n) * 256 + m]);
      us4 pv = *reinterpret_cast<const us4*>(&g.PET[(size_t)n * 256 + m]);
      facc4 v0 = acc0[mi][ni], v1 = acc1[mi][ni];
      float bb0[4] = {b0.x, b0.y, b0.z, b0.w};
      float bb1[4] = {b1.x, b1.y, b1.z, b1.w};
      us4 pk;
#pragma unroll
      for (int r = 0; r < 4; ++r) {
        float gg = 2.f * bf2f(gv[r]), pp = bf2f(pv[r]);
        float r0 = v0[r] + bb0[r] + gg + 2.f * pp;
        float r1 = v1[r] + bb1[r] + gg + 4.f * pp;
        pk[r] = f2bf(a * r0 + (1.f - a) * r1);
      }
      *reinterpret_cast<us4*>(&g.FUSED[(bq + n) * 256 + m]) = pk;
    }
  }
}

// ================= up-conv: M=384 one-pass, B = FUSED via gload16, f32 out =================
__global__ __launch_bounds__(384) void gemm_up(const unsigned short* __restrict__ W,
                                               const unsigned short* __restrict__ FUSED,
                                               const float* __restrict__ bias,
                                               float* __restrict__ out) {
  __shared__ unsigned short As[24576]; // [384][64]
  __shared__ unsigned short Bs[4096];  // [64][64]
  const int t = threadIdx.x;
  const int lane = t & 63, w = t >> 6; // w 0..5
  const int b = blockIdx.z;
  const int n0 = blockIdx.x * 64;

  const unsigned short* asrc[8];
  unsigned short* adst[8];
#pragma unroll
  for (int i = 0; i < 8; ++i) {
    int c = t + 384 * i;
    int row = c >> 3;
    int k8 = (c & 7) ^ (row & 7);
    asrc[i] = W + (size_t)row * 256 + k8 * 8;
    adst[i] = &As[w * 512 + i * 3072];
  }
  const bool bst = t < 256;
  const unsigned short* bsrc[2];
  unsigned short* bdst[2];
  if (bst) {
#pragma unroll
    for (int i = 0; i < 2; ++i) {
      int c = t + 256 * i;
      int n = c >> 3;
      int k8 = (c & 7) ^ (n & 7);
      bsrc[i] = FUSED + ((size_t)b * NQ + n0 + n) * 256 + k8 * 8;
      bdst[i] = &Bs[w * 512 + i * 2048];
    }
  }

  const int l15 = lane & 15, l4 = lane >> 4;
  facc4 acc[4][4];
#pragma unroll
  for (int i = 0; i < 4; ++i)
#pragma unroll
    for (int j = 0; j < 4; ++j) acc[i][j] = facc4{0.f, 0.f, 0.f, 0.f};

  for (int k0 = 0; k0 < 256; k0 += 64) {
    if (k0) __syncthreads();
#pragma unroll
    for (int i = 0; i < 8; ++i) {
      gload16(asrc[i], adst[i]);
      asrc[i] += 64;
    }
    if (bst) {
      gload16(bsrc[0], bdst[0]); bsrc[0] += 64;
      gload16(bsrc[1], bdst[1]); bsrc[1] += 64;
    }
    __syncthreads();
#pragma unroll
    for (int kk = 0; kk < 2; ++kk) {
      bfrag8 af[4], bf[4];
#pragma unroll
      for (int mi = 0; mi < 4; ++mi) {
        int row = w * 64 + mi * 16 + l15;
        af[mi] = *reinterpret_cast<const bfrag8*>(&As[row * 64 + (((kk * 4 + l4) ^ (row & 7)) * 8)]);
      }
#pragma unroll
      for (int ni = 0; ni < 4; ++ni) {
        int row = ni * 16 + l15;
        bf[ni] = *reinterpret_cast<const bfrag8*>(&Bs[row * 64 + (((kk * 4 + l4) ^ (row & 7)) * 8)]);
      }
#pragma unroll
      for (int mi = 0; mi < 4; ++mi)
#pragma unroll
        for (int ni = 0; ni < 4; ++ni)
          acc[mi][ni] = __builtin_amdgcn_mfma_f32_16x16x32_bf16(af[mi], bf[ni], acc[mi][ni], 0, 0, 0);
    }
  }
#pragma unroll
  for (int mi = 0; mi < 4; ++mi) {
    int m = w * 64 + mi * 16 + l4 * 4;
    if (m >= 320) continue;
#pragma unroll
    for (int ni = 0; ni < 4; ++ni) {
      int n = n0 + ni * 16 + l15;
      facc4 v = acc[mi][ni];
#pragma unroll
      for (int r = 0; r < 4; ++r)
        out[((size_t)b * 320 + m + r) * NQ + n] = v[r] + bias[m + r];
    }
  }
}

// ================= alpha gate =================
__global__ __launch_bounds__(256) void k_alpha(const unsigned short* __restrict__ G,
                                               const float* __restrict__ w1,
                                               const float* __restrict__ b1,
                                               const float* __restrict__ w2,
                                               const float* __restrict__ b2,
                                               float* __restrict__ partial) {
  int b = blockIdx.y;
  int qbase = blockIdx.x * 16;
  __shared__ float gs[16][256];
  __shared__ float wsum[4];
  int t = threadIdx.x;
  const unsigned short* gp = G + ((size_t)b * NQ + qbase) * 256;
#pragma unroll
  for (int i = t; i < 512; i += 256) {
    bfrag8 v = *reinterpret_cast<const bfrag8*>(&gp[i * 8]);
    int row = i >> 5, col = (i & 31) * 8;
#pragma unroll
    for (int j = 0; j < 8; ++j) gs[row][col + j] = bf2f((unsigned short)v[j]);
  }
  __syncthreads();
  int wv = t >> 6, lane = t & 63;
  float a0 = 0.f, a1 = 0.f, a2 = 0.f, a3 = 0.f;
  const float* g0 = gs[wv * 4 + 0];
  const float* g1 = gs[wv * 4 + 1];
  const float* g2 = gs[wv * 4 + 2];
  const float* g3 = gs[wv * 4 + 3];
#pragma unroll 4
  for (int k = 0; k < 256; ++k) {
    float wk = w1[k * 64 + lane];
    a0 = fmaf(g0[k], wk, a0); a1 = fmaf(g1[k], wk, a1);
    a2 = fmaf(g2[k], wk, a2); a3 = fmaf(g3[k], wk, a3);
  }
  float b1l = b1[lane], w2l = w2[lane];
  a0 = fmaxf(a0 + b1l, 0.f) * w2l; a1 = fmaxf(a1 + b1l, 0.f) * w2l;
  a2 = fmaxf(a2 + b1l, 0.f) * w2l; a3 = fmaxf(a3 + b1l, 0.f) * w2l;
#pragma unroll
  for (int off = 32; off; off >>= 1) {
    a0 += __shfl_xor(a0, off); a1 += __shfl_xor(a1, off);
    a2 += __shfl_xor(a2, off); a3 += __shfl_xor(a3, off);
  }
  if (lane == 0) {
    float bb = b2[0];
    float s = 1.f / (1.f + expf(-(a0 + bb))) + 1.f / (1.f + expf(-(a1 + bb))) +
              1.f / (1.f + expf(-(a2 + bb))) + 1.f / (1.f + expf(-(a3 + bb)));
    wsum[wv] = s;
  }
  __syncthreads();
  if (t == 0) partial[(size_t)b * 256 + blockIdx.x] = wsum[0] + wsum[1] + wsum[2] + wsum[3];
}

__global__ __launch_bounds__(256) void k_alpha_fin(const float* __restrict__ partial,
                                                   float* __restrict__ afin,
                                                   float* __restrict__ out_a) {
  int b = blockIdx.x;
  __shared__ float sm[256];
  sm[threadIdx.x] = partial[(size_t)b * 256 + threadIdx.x];
  __syncthreads();
  for (int st = 128; st; st >>= 1) {
    if (threadIdx.x < st) sm[threadIdx.x] += sm[threadIdx.x + st];
    __syncthreads();
  }
  if (threadIdx.x == 0) {
    float a = sm[0] * (1.f / 4096.f);
    afin[b] = a;
    out_a[b] = a;
  }
}

extern "C" void kernel_launch(void* const* d_in, const int* in_sizes, int n_in,
                              void* d_out, int out_size, void* d_ws, size_t ws_size,
                              hipStream_t stream) {
  const float* ground = (const float*)d_in[0];
  const float* sat = (const float*)d_in[1];
  const float* osm = (const float*)d_in[2];
  const float* gc_w = (const float*)d_in[3];
  const float* gc_b = (const float*)d_in[4];
  const float* sc_w = (const float*)d_in[5];
  const float* sc_b = (const float*)d_in[6];
  const float* up_w = (const float*)d_in[7];
  const float* up_b = (const float*)d_in[8];
  const float* a_w1 = (const float*)d_in[9];
  const float* a_b1 = (const float*)d_in[10];
  const float* a_w2 = (const float*)d_in[11];
  const float* a_b2 = (const float*)d_in[12];
  const float* vp_w[2] = {(const float*)d_in[13], (const float*)d_in[21]};
  const float* vp_b[2] = {(const float*)d_in[14], (const float*)d_in[22]};
  const float* so_w[2] = {(const float*)d_in[15], (const float*)d_in[23]};
  const float* so_b[2] = {(const float*)d_in[16], (const float*)d_in[24]};
  const float* aw_w[2] = {(const float*)d_in[17], (const float*)d_in[25]};
  const float* aw_b[2] = {(const float*)d_in[18], (const float*)d_in[26]};
  const float* op_w[2] = {(const float*)d_in[19], (const float*)d_in[27]};
  const float* op_b[2] = {(const float*)d_in[20], (const float*)d_in[28]};

  char* wsb = (char*)d_ws;
  const size_t MBy = 1 << 20;
  unsigned short* PET  = (unsigned short*)(wsb);                       // 2 MB
  unsigned short* WG   = (unsigned short*)(wsb + 2 * MBy);             // 512 KB
  unsigned short* WV0  = (unsigned short*)(wsb + 2 * MBy + 524288);    // 160 KB
  unsigned short* WV1  = (unsigned short*)(wsb + 2 * MBy + 786432);    // 160 KB
  unsigned short* WUP  = (unsigned short*)(wsb + 3 * MBy);             // 192 KB
  unsigned short* OPT0 = (unsigned short*)(wsb + 3 * MBy + 262144);    // 128 KB
  unsigned short* OPT1 = (unsigned short*)(wsb + 3 * MBy + 393216);    // 128 KB
  unsigned short* SOW0 = (unsigned short*)(wsb + 3 * MBy + 524288);    // 64 KB
  unsigned short* SOW1 = (unsigned short*)(wsb + 3 * MBy + 589824);    // 64 KB
  unsigned short* PESO0 = (unsigned short*)(wsb + 4 * MBy);            // 1 MB
  unsigned short* PESO1 = (unsigned short*)(wsb + 5 * MBy);            // 1 MB
  float* SOB0 = (float*)(wsb + 6 * MBy);
  float* SOB1 = (float*)(wsb + 6 * MBy + 4096);
  float* BV0  = (float*)(wsb + 6 * MBy + 8192);
  float* BV1  = (float*)(wsb + 6 * MBy + 12288);
  float* BUPP = (float*)(wsb + 6 * MBy + 16384);
  float* PART = (float*)(wsb + 6 * MBy + 32768);  // 8 KB
  float* AFIN = (float*)(wsb + 6 * MBy + 65536);
  unsigned short* G     = (unsigned short*)(wsb + 8 * MBy);    // 16 MB
  unsigned short* VP0b  = (unsigned short*)(wsb + 24 * MBy);   // 16 MB
  unsigned short* VP1b  = (unsigned short*)(wsb + 40 * MBy);   // 16 MB
  unsigned short* SW    = (unsigned short*)(wsb + 56 * MBy);   // 16 MB [2][B][Q][128]
  unsigned short* FUSED = (unsigned short*)(wsb + 72 * MBy);   // 16 MB

  float* out32 = (float*)d_out;
  float* out_a = out32 + (size_t)NB * 320 * NQ;

  dim3 blk(256);

  // ---- prep ----
  {
    PrepArgs p;
    p.gc_w = gc_w; p.up_w = up_w; p.up_b = up_b;
    p.so_w0 = so_w[0]; p.so_b0 = so_b[0]; p.so_w1 = so_w[1]; p.so_b1 = so_b[1];
    p.aw_w0 = aw_w[0]; p.aw_b0 = aw_b[0]; p.aw_w1 = aw_w[1]; p.aw_b1 = aw_b[1];
    p.op_w0 = op_w[0]; p.op_w1 = op_w[1];
    p.PET = PET; p.WG = WG; p.WUP = WUP;
    p.OPT0 = OPT0; p.OPT1 = OPT1; p.SOW0 = SOW0; p.SOW1 = SOW1;
    p.BUPP = BUPP; p.SOB0 = SOB0; p.SOB1 = SOB1;
    mega_prep<<<dim3(6273), blk, 0, stream>>>(p);
  }
  k_wv<<<dim3(16, 2), blk, 0, stream>>>(vp_w[0], vp_b[0], vp_w[1], vp_b[1],
                                        sc_w, sc_b, WV0, WV1, BV0, BV1);

  // ---- PESO_br = s_br*(PE @ soaw_w_br) + bias_br ----
  {
    GArgs a = {};
    a.W[0] = SOW0; a.W[1] = SOW1;
    a.X[0] = PET;  a.X[1] = PET;
    a.bias[0] = SOB0; a.bias[1] = SOB1;
    a.out[0] = PESO0; a.out[1] = PESO1;
    a.rscale[0] = 1.f; a.rscale[1] = 2.f;
    a.K = 256; a.ldm = 128; a.bmask = 0; a.brshift = 0;
    gemm_bf16<1><<<dim3(32, 1, 2), blk, 0, stream>>>(a);
  }

  // ---- gconv: fused transpose from f32 ----
  {
    NArgs a = {};
    a.W[0] = WG; a.W[1] = WG;
    a.X[0] = ground; a.X[1] = ground;
    a.bias[0] = gc_b; a.bias[1] = gc_b;
    a.out[0] = G; a.out[1] = G;
    a.K = 1024; a.zmask = 7; a.zshift = 31;
    gemm_n64<<<dim3(64, 1, NB), blk, 0, stream>>>(a);
  }

  // ---- alpha ----
  k_alpha<<<dim3(256, NB), blk, 0, stream>>>(G, a_w1, a_b1, a_w2, a_b2, PART);
  k_alpha_fin<<<dim3(NB), blk, 0, stream>>>(PART, AFIN, out_a);

  // ---- SW_br = G @ soaw_w_br + PESO_br ----
  {
    GArgs a = {};
    a.W[0] = SOW0; a.W[1] = SOW1;
    a.X[0] = G; a.X[1] = G;
    a.out[0] = SW; a.out[1] = SW + (size_t)NB * NQ * 128;
    a.res[0] = PESO0; a.res[1] = PESO1;
    a.rscale[0] = 1.f; a.rscale[1] = 1.f;
    a.K = 256; a.ldm = 128; a.bmask = 7; a.brshift = 3;
    gemm_bf16<2><<<dim3(32, 1, 16), blk, 0, stream>>>(a);
  }

  // ---- VP_br = sat/osm @ WV_br + BV_br (fused transpose from f32) ----
  {
    NArgs a = {};
    a.W[0] = WV0; a.W[1] = WV1;
    a.X[0] = sat; a.X[1] = osm;
    a.bias[0] = BV0; a.bias[1] = BV1;
    a.out[0] = VP0b; a.out[1] = VP1b;
    a.K = 320; a.zmask = 7; a.zshift = 3;
    gemm_n64<<<dim3(64, 1, 16), blk, 0, stream>>>(a);
  }

  // ---- fused tail: gather + dual op-proj + blend -> FUSED ----
  {
    TArgs a;
    a.VP0 = VP0b; a.VP1 = VP1b; a.SWb = SW;
    a.OPT0 = OPT0; a.OPT1 = OPT1;
    a.opb0 = op_b[0]; a.opb1 = op_b[1];
    a.G = G; a.PET = PET; a.afin = AFIN;
    a.FUSED = FUSED;
    k_tail<<<dim3(64, NB), blk, 0, stream>>>(a);
  }

  // ---- up conv -> f32 out ----
  gemm_up<<<dim3(64, 1, NB), dim3(384), 0, stream>>>(WUP, FUSED, BUPP, out32);
}

// Round 9
// 272.127 us; speedup vs baseline: 1.4167x; 1.4167x over previous
//
#include <hip/hip_runtime.h>
#include <cstddef>
#include <cstdint>

#define NB 8
#define NQ 4096

typedef __attribute__((ext_vector_type(8))) short bfrag8;
typedef __attribute__((ext_vector_type(4))) float facc4;
typedef __attribute__((ext_vector_type(4))) unsigned short us4;
typedef __attribute__((ext_vector_type(8))) unsigned short us8;

__device__ __forceinline__ float bf2f(unsigned short u) {
  union { unsigned int i; float f; } v; v.i = ((unsigned int)u) << 16; return v.f;
}
__device__ __forceinline__ unsigned short f2bf(float f) {
  union { float f; unsigned int i; } v; v.f = f;
  unsigned int r = v.i + 0x7FFFu + ((v.i >> 16) & 1u);
  return (unsigned short)(r >> 16);
}
__device__ __forceinline__ void gload16(const void* g, void* l) {
  __builtin_amdgcn_global_load_lds(
      (const __attribute__((address_space(1))) void*)g,
      (__attribute__((address_space(3))) void*)l, 16, 0, 0);
}

// ================= mega prep =================
struct PrepArgs {
  const float *gc_w, *up_w, *up_b;
  const float *so_w0, *so_b0, *so_w1, *so_b1;
  const float *aw_w0, *aw_b0, *aw_w1, *aw_b1;
  const float *a_w1;
  const float *op_w0, *op_w1;
  unsigned short *PET, *WG, *WUP, *OPT0, *OPT1, *SOWS;
  float *BUPP, *SOBS;
};

__global__ __launch_bounds__(256) void mega_prep(PrepArgs p) {
  const int blk = blockIdx.x, t = threadIdx.x;
  if (blk < 4096) {
    int idx = blk * 256 + t;
    int q = idx >> 8, c = idx & 255;
    int h = q >> 6, w = q & 63;
    int k = c >> 2, m = c & 3;
    float dv = expf((float)(2 * k) * (-9.210340371976184f / 128.0f));
    float arg = ((m < 2) ? (float)w : (float)h) * dv;
    p.PET[idx] = f2bf(((m & 1) == 0) ? sinf(arg) : cosf(arg));
  } else if (blk < 5120) {
    int i = (blk - 4096) * 256 + t;
    p.WG[i] = f2bf(p.gc_w[i]);
  } else if (blk < 5504) {
    int i = (blk - 5120) * 256 + t;
    int m = i >> 8, k = i & 255;
    p.WUP[i] = (m < 320) ? f2bf(p.up_w[m * 256 + k]) : 0;
  } else if (blk < 5505) {
    p.BUPP[t] = (t < 320) ? p.up_b[t] : 0.f;
    if (t < 128) {
      int i2 = 256 + t;
      p.BUPP[i2] = (i2 < 320) ? p.up_b[i2] : 0.f;
    }
  } else if (blk < 6017) {
    int i = (blk - 5505) * 256 + t;
    int which = i >> 16, j = i & 65535;
    int o = j >> 8, k = j & 255;
    (which ? p.OPT1 : p.OPT0)[j] = f2bf((which ? p.op_w1 : p.op_w0)[k * 256 + o]);
  } else {
    // SOWS [384][256]: rows 0-127 br0 (so|aw), 128-255 br1, 256-319 a_w1^T, 320-383 zero
    int i = (blk - 6017) * 256 + t;  // < 98304
    int row = i >> 8, k = i & 255;
    float v = 0.f;
    if (row < 256) {
      int br = row >> 7, rr = row & 127;
      const float* sw = br ? p.so_w1 : p.so_w0;
      const float* aw = br ? p.aw_w1 : p.aw_w0;
      if (rr < 64) v = sw[k * 64 + rr];
      else if (rr < 96) v = aw[k * 32 + (rr - 64)];
    } else if (row < 320) {
      v = p.a_w1[k * 64 + (row - 256)];
    }
    p.SOWS[i] = f2bf(v);
    if (i < 256) {
      int br = i >> 7, rr = i & 127;
      const float* sb = br ? p.so_b1 : p.so_b0;
      const float* ab = br ? p.aw_b1 : p.aw_b0;
      p.SOBS[i] = (rr < 64) ? sb[rr] : ((rr < 96) ? ab[rr - 64] : 0.f);
    }
  }
}

// ================= WV/BV: tiled LDS-staged small GEMM =================
__global__ __launch_bounds__(256) void k_wv(const float* __restrict__ vp_w0,
                                            const float* __restrict__ vp_b0,
                                            const float* __restrict__ vp_w1,
                                            const float* __restrict__ vp_b1,
                                            const float* __restrict__ sc_w,
                                            const float* __restrict__ sc_b,
                                            unsigned short* __restrict__ WV0,
                                            unsigned short* __restrict__ WV1,
                                            float* __restrict__ BV0,
                                            float* __restrict__ BV1) {
  const int br = blockIdx.y, kt = blockIdx.x, k0 = kt * 20, t = threadIdx.x;
  const float* vp = br ? vp_w1 : vp_w0;
  unsigned short* WV = br ? WV1 : WV0;
  __shared__ float vt[32][256];
  __shared__ float st[32][20];
  __shared__ float sb[32];
  float acc[20] = {};
  float accB = 0.f;
  for (int c0 = 0; c0 < 256; c0 += 32) {
    __syncthreads();
#pragma unroll
    for (int cc = 0; cc < 32; ++cc)
      vt[cc][t] = vp[(size_t)(c0 + cc) * 256 + t];
    for (int i = t; i < 640; i += 256)
      st[i / 20][i % 20] = sc_w[(size_t)(c0 + i / 20) * 320 + k0 + (i % 20)];
    if (t < 32) sb[t] = sc_b[c0 + t];
    __syncthreads();
#pragma unroll
    for (int cc = 0; cc < 32; ++cc) {
      float v = vt[cc][t];
      accB = fmaf(v, sb[cc], accB);
#pragma unroll
      for (int j = 0; j < 20; ++j)
        acc[j] = fmaf(v, st[cc][j], acc[j]);
    }
  }
#pragma unroll
  for (int j = 0; j < 20; ++j) WV[(size_t)t * 320 + k0 + j] = f2bf(acc[j]);
  if (kt == 0) (br ? BV1 : BV0)[t] = (br ? vp_b1 : vp_b0)[t] + accB;
}

// ================= 128x128 GEMM (PESOS dispatch) =================
struct GArgs {
  const unsigned short* W[2];
  const unsigned short* X[2];
  const float* bias[2];
  void* out[2];
  float rscale[2];
  int K, ldm, bmask, brshift;
};
// MODE 1: out = rscale*acc + bias (bf16)
template <int MODE>
__global__ __launch_bounds__(256) void gemm_bf16(GArgs g) {
  __shared__ unsigned short As[8192];
  __shared__ unsigned short Bs[8192];
  const int t = threadIdx.x;
  const int lane = t & 63, w = t >> 6;
  const int z = blockIdx.z;
  const int b = z & g.bmask, br = z >> g.brshift;
  const int K = g.K;
  const int n0 = blockIdx.x * 128;
  const unsigned short* W = g.W[br];
  const unsigned short* Xb = g.X[br] + (size_t)b * NQ * K;

  const unsigned short* asrc[4];
  const unsigned short* bsrc[4];
  unsigned short* adst[4];
  unsigned short* bdst[4];
#pragma unroll
  for (int i = 0; i < 4; ++i) {
    int cid = i * 256 + t;
    int row = cid >> 3;
    int cc = (cid & 7) ^ (row & 7);
    asrc[i] = W + (size_t)row * K + cc * 8;
    bsrc[i] = Xb + (size_t)(n0 + row) * K + cc * 8;
    adst[i] = &As[i * 2048 + w * 512];
    bdst[i] = &Bs[i * 2048 + w * 512];
  }
  const int wm = (w >> 1) * 64, wn = (w & 1) * 64;
  const int l15 = lane & 15, l4 = lane >> 4;
  facc4 acc[4][4];
#pragma unroll
  for (int i = 0; i < 4; ++i)
#pragma unroll
    for (int j = 0; j < 4; ++j) acc[i][j] = facc4{0.f, 0.f, 0.f, 0.f};

  for (int k0 = 0; k0 < K; k0 += 64) {
    if (k0) __syncthreads();
#pragma unroll
    for (int i = 0; i < 4; ++i) {
      gload16(asrc[i], adst[i]);
      gload16(bsrc[i], bdst[i]);
      asrc[i] += 64; bsrc[i] += 64;
    }
    __syncthreads();
#pragma unroll
    for (int kk = 0; kk < 2; ++kk) {
      bfrag8 af[4], bf[4];
#pragma unroll
      for (int mi = 0; mi < 4; ++mi) {
        int row = wm + mi * 16 + l15;
        af[mi] = *reinterpret_cast<const bfrag8*>(&As[row * 64 + (((kk * 4 + l4) ^ (row & 7)) * 8)]);
      }
#pragma unroll
      for (int ni = 0; ni < 4; ++ni) {
        int row = wn + ni * 16 + l15;
        bf[ni] = *reinterpret_cast<const bfrag8*>(&Bs[row * 64 + (((kk * 4 + l4) ^ (row & 7)) * 8)]);
      }
#pragma unroll
      for (int mi = 0; mi < 4; ++mi)
#pragma unroll
        for (int ni = 0; ni < 4; ++ni)
          acc[mi][ni] = __builtin_amdgcn_mfma_f32_16x16x32_bf16(af[mi], bf[ni], acc[mi][ni], 0, 0, 0);
    }
  }
  const size_t bq = (size_t)b * NQ;
#pragma unroll
  for (int mi = 0; mi < 4; ++mi) {
#pragma unroll
    for (int ni = 0; ni < 4; ++ni) {
      int m = wm + mi * 16 + l4 * 4;
      int n = n0 + wn + ni * 16 + l15;
      facc4 v = acc[mi][ni];
      unsigned short* o16 = (unsigned short*)g.out[br];
      float sc = g.rscale[br];
      float4 bv = *reinterpret_cast<const float4*>(&g.bias[br][m]);
      us4 pk;
      pk[0] = f2bf(v[0] * sc + bv.x); pk[1] = f2bf(v[1] * sc + bv.y);
      pk[2] = f2bf(v[2] * sc + bv.z); pk[3] = f2bf(v[3] * sc + bv.w);
      *reinterpret_cast<us4*>(&o16[(bq + n) * g.ldm + m]) = pk;
    }
  }
}

// ================= N=64 full-M GEMM (gconv / VP / op-proj) =================
struct NArgs {
  const unsigned short* W[2];
  const void* X[2];
  const float* bias[2];
  void* out[2];
  const unsigned short* G;
  const unsigned short* PET;
  const float* afin;
  float rs[2];
  int K, zmask, zshift;
};
// BSRC 0: X bf16 [b][4096][K] via global_load_lds (source-swizzled)
// BSRC 1: X f32 [b][K][4096] reg-staged transpose+convert
// MODE 0: out bf16 = acc + bias
// MODE 6: out_br bf16 = s_br * (acc + bias + 2*G + rs_br*PET), s0=a, s1=1-a
template <int BSRC, int MODE>
__global__ __launch_bounds__(256) void gemm_n64(NArgs g) {
  __shared__ unsigned short As[16384]; // [256][64] swizzled
  __shared__ unsigned short Bs[4096];  // [64][64] swizzled
  const int t = threadIdx.x;
  const int lane = t & 63, w = t >> 6;
  const int z = blockIdx.z;
  const int b = z & g.zmask, br = z >> g.zshift;
  const int K = g.K;
  const int n0 = blockIdx.x * 64;

  const unsigned short* W = g.W[br];
  const unsigned short* asrc[8];
  unsigned short* adst[8];
#pragma unroll
  for (int i = 0; i < 8; ++i) {
    int c = t + 256 * i;
    int row = c >> 3;
    int k8 = (c & 7) ^ (row & 7);
    asrc[i] = W + (size_t)row * K + k8 * 8;
    adst[i] = &As[w * 512 + i * 2048];
  }

  const unsigned short* bsrc16[2];
  unsigned short* bdst16[2];
  const float* bsrcf = nullptr;
  const int kb = t >> 4, nb = t & 15;
  if constexpr (BSRC == 0) {
    const unsigned short* Xh = (const unsigned short*)g.X[br];
#pragma unroll
    for (int i = 0; i < 2; ++i) {
      int c = t + 256 * i;
      int n = c >> 3;
      int k8 = (c & 7) ^ (n & 7);
      bsrc16[i] = Xh + ((size_t)b * NQ + n0 + n) * K + k8 * 8;
      bdst16[i] = &Bs[w * 512 + i * 2048];
    }
  } else {
    const float* Xf = (const float*)g.X[br];
    bsrcf = Xf + (size_t)b * K * NQ + (size_t)(kb * 4) * NQ + n0 + nb * 4;
  }

  const int l15 = lane & 15, l4 = lane >> 4;
  facc4 acc[4][4];
#pragma unroll
  for (int i = 0; i < 4; ++i)
#pragma unroll
    for (int j = 0; j < 4; ++j) acc[i][j] = facc4{0.f, 0.f, 0.f, 0.f};

  for (int k0 = 0; k0 < K; k0 += 64) {
    if (k0) __syncthreads();
#pragma unroll
    for (int i = 0; i < 8; ++i) {
      gload16(asrc[i], adst[i]);
      asrc[i] += 64;
    }
    if constexpr (BSRC == 0) {
      gload16(bsrc16[0], bdst16[0]); bsrc16[0] += 64;
      gload16(bsrc16[1], bdst16[1]); bsrc16[1] += 64;
    } else {
      float vv[4][4];
#pragma unroll
      for (int r = 0; r < 4; ++r) {
        float4 v = *reinterpret_cast<const float4*>(bsrcf + (size_t)k0 * NQ + (size_t)r * NQ);
        vv[r][0] = v.x; vv[r][1] = v.y; vv[r][2] = v.z; vv[r][3] = v.w;
      }
#pragma unroll
      for (int c = 0; c < 4; ++c) {
        int n = nb * 4 + c;
        us4 pk;
        pk[0] = f2bf(vv[0][c]); pk[1] = f2bf(vv[1][c]);
        pk[2] = f2bf(vv[2][c]); pk[3] = f2bf(vv[3][c]);
        int off = n * 64 + (((kb >> 1) ^ (n & 7)) * 8) + (kb & 1) * 4;
        *reinterpret_cast<us4*>(&Bs[off]) = pk;
      }
    }
    __syncthreads();
#pragma unroll
    for (int kk = 0; kk < 2; ++kk) {
      bfrag8 af[4], bf[4];
#pragma unroll
      for (int mi = 0; mi < 4; ++mi) {
        int row = w * 64 + mi * 16 + l15;
        af[mi] = *reinterpret_cast<const bfrag8*>(&As[row * 64 + (((kk * 4 + l4) ^ (row & 7)) * 8)]);
      }
#pragma unroll
      for (int ni = 0; ni < 4; ++ni) {
        int row = ni * 16 + l15;
        bf[ni] = *reinterpret_cast<const bfrag8*>(&Bs[row * 64 + (((kk * 4 + l4) ^ (row & 7)) * 8)]);
      }
#pragma unroll
      for (int mi = 0; mi < 4; ++mi)
#pragma unroll
        for (int ni = 0; ni < 4; ++ni)
          acc[mi][ni] = __builtin_amdgcn_mfma_f32_16x16x32_bf16(af[mi], bf[ni], acc[mi][ni], 0, 0, 0);
    }
  }

  const size_t bq = (size_t)b * NQ;
  unsigned short* o16 = (unsigned short*)g.out[br];
#pragma unroll
  for (int mi = 0; mi < 4; ++mi) {
#pragma unroll
    for (int ni = 0; ni < 4; ++ni) {
      int m = w * 64 + mi * 16 + l4 * 4;
      int n = n0 + ni * 16 + l15;
      facc4 v = acc[mi][ni];
      float4 bv = *reinterpret_cast<const float4*>(&g.bias[br][m]);
      float rv[4] = {v[0] + bv.x, v[1] + bv.y, v[2] + bv.z, v[3] + bv.w};
      if constexpr (MODE == 6) {
        float a = g.afin[b];
        float s = br ? (1.f - a) : a;
        float rsc = g.rs[br];
        us4 gv = *reinterpret_cast<const us4*>(&g.G[(bq + n) * 256 + m]);
        us4 pv = *reinterpret_cast<const us4*>(&g.PET[(size_t)n * 256 + m]);
#pragma unroll
        for (int r = 0; r < 4; ++r)
          rv[r] = s * (rv[r] + 2.f * bf2f(gv[r]) + rsc * bf2f(pv[r]));
      }
      us4 pk;
#pragma unroll
      for (int r = 0; r < 4; ++r) pk[r] = f2bf(rv[r]);
      *reinterpret_cast<us4*>(&o16[(bq + n) * 256 + m]) = pk;
    }
  }
}

// ================= SW + alpha fused: M=384 (SW0|SW1|alpha-hidden), B=G =================
struct SAArgs {
  const unsigned short *W;      // SOWS [384][256]
  const unsigned short *G;      // [8][4096][256]
  const unsigned short *PESOS;  // [4096][256]
  const float *b1, *w2, *b2;
  unsigned short *SWS;          // [8][4096][256]
  float *partial;               // [8][64]
};
__global__ __launch_bounds__(384) void k_swalpha(SAArgs g) {
  __shared__ unsigned short As[24576]; // [384][64] swizzled
  __shared__ unsigned short Bs[4096];  // [64][64] swizzled
  const int t = threadIdx.x;
  const int lane = t & 63, w = t >> 6; // w 0..5
  const int b = blockIdx.z;
  const int n0 = blockIdx.x * 64;

  const unsigned short* asrc[8];
  unsigned short* adst[8];
#pragma unroll
  for (int i = 0; i < 8; ++i) {
    int c = t + 384 * i;
    int row = c >> 3;
    int k8 = (c & 7) ^ (row & 7);
    asrc[i] = g.W + (size_t)row * 256 + k8 * 8;
    adst[i] = &As[w * 512 + i * 3072];
  }
  const bool bst = t < 256;
  const unsigned short* bsrc[2];
  unsigned short* bdst[2];
  if (bst) {
#pragma unroll
    for (int i = 0; i < 2; ++i) {
      int c = t + 256 * i;
      int n = c >> 3;
      int k8 = (c & 7) ^ (n & 7);
      bsrc[i] = g.G + ((size_t)b * NQ + n0 + n) * 256 + k8 * 8;
      bdst[i] = &Bs[w * 512 + i * 2048];
    }
  }

  const int l15 = lane & 15, l4 = lane >> 4;
  facc4 acc[4][4];
#pragma unroll
  for (int i = 0; i < 4; ++i)
#pragma unroll
    for (int j = 0; j < 4; ++j) acc[i][j] = facc4{0.f, 0.f, 0.f, 0.f};

  for (int k0 = 0; k0 < 256; k0 += 64) {
    if (k0) __syncthreads();
#pragma unroll
    for (int i = 0; i < 8; ++i) {
      gload16(asrc[i], adst[i]);
      asrc[i] += 64;
    }
    if (bst) {
      gload16(bsrc[0], bdst[0]); bsrc[0] += 64;
      gload16(bsrc[1], bdst[1]); bsrc[1] += 64;
    }
    __syncthreads();
    if (w < 5) {
#pragma unroll
      for (int kk = 0; kk < 2; ++kk) {
        bfrag8 af[4], bf[4];
#pragma unroll
        for (int mi = 0; mi < 4; ++mi) {
          int row = w * 64 + mi * 16 + l15;
          af[mi] = *reinterpret_cast<const bfrag8*>(&As[row * 64 + (((kk * 4 + l4) ^ (row & 7)) * 8)]);
        }
#pragma unroll
        for (int ni = 0; ni < 4; ++ni) {
          int row = ni * 16 + l15;
          bf[ni] = *reinterpret_cast<const bfrag8*>(&Bs[row * 64 + (((kk * 4 + l4) ^ (row & 7)) * 8)]);
        }
#pragma unroll
        for (int mi = 0; mi < 4; ++mi)
#pragma unroll
          for (int ni = 0; ni < 4; ++ni)
            acc[mi][ni] = __builtin_amdgcn_mfma_f32_16x16x32_bf16(af[mi], bf[ni], acc[mi][ni], 0, 0, 0);
      }
    }
  }

  const size_t bq = (size_t)b * NQ;
  if (w < 4) {
    // SW rows: out = acc + PESOS[n][m]  (PESOS already has scale*PE@SOW + bias)
#pragma unroll
    for (int mi = 0; mi < 4; ++mi) {
#pragma unroll
      for (int ni = 0; ni < 4; ++ni) {
        int m = w * 64 + mi * 16 + l4 * 4;
        int n = n0 + ni * 16 + l15;
        facc4 v = acc[mi][ni];
        us4 rr = *reinterpret_cast<const us4*>(&g.PESOS[(size_t)n * 256 + m]);
        us4 pk;
#pragma unroll
        for (int r = 0; r < 4; ++r) pk[r] = f2bf(v[r] + bf2f(rr[r]));
        *reinterpret_cast<us4*>(&g.SWS[(bq + n) * 256 + m]) = pk;
      }
    }
  } else if (w == 4) {
    // alpha rows: hid = mi*16 + l4*4 + r ; per q: sum relu(h+b1)*w2 -> sigmoid -> block sum
    float b2v = g.b2[0];
    float ssum = 0.f;
#pragma unroll
    for (int ni = 0; ni < 4; ++ni) {
      float s = 0.f;
#pragma unroll
      for (int mi = 0; mi < 4; ++mi) {
#pragma unroll
        for (int r = 0; r < 4; ++r) {
          int hid = mi * 16 + l4 * 4 + r;
          s += fmaxf(acc[mi][ni][r] + g.b1[hid], 0.f) * g.w2[hid];
        }
      }
      s += __shfl_xor(s, 16);
      s += __shfl_xor(s, 32);
      ssum += 1.f / (1.f + expf(-(s + b2v)));
    }
    ssum += __shfl_xor(ssum, 1);
    ssum += __shfl_xor(ssum, 2);
    ssum += __shfl_xor(ssum, 4);
    ssum += __shfl_xor(ssum, 8);
    if (lane == 0) g.partial[b * 64 + blockIdx.x] = ssum;
  }
}

__global__ __launch_bounds__(64) void k_alpha_fin(const float* __restrict__ partial,
                                                  float* __restrict__ afin,
                                                  float* __restrict__ out_a) {
  int b = blockIdx.x;
  float s = partial[b * 64 + threadIdx.x];
#pragma unroll
  for (int off = 32; off; off >>= 1) s += __shfl_xor(s, off);
  if (threadIdx.x == 0) {
    float a = s * (1.f / 4096.f);
    afin[b] = a;
    out_a[b] = a;
  }
}

// ================= up-conv: M=384 one-pass, B = blend(S0+S1), f32 out =================
__global__ __launch_bounds__(384) void gemm_up(const unsigned short* __restrict__ W,
                                               const unsigned short* __restrict__ S0,
                                               const unsigned short* __restrict__ S1,
                                               const float* __restrict__ bias,
                                               float* __restrict__ out) {
  __shared__ unsigned short As[24576]; // [384][64]
  __shared__ unsigned short Bs[4096];  // [64][64]
  const int t = threadIdx.x;
  const int lane = t & 63, w = t >> 6;
  const int b = blockIdx.z;
  const int n0 = blockIdx.x * 64;

  const unsigned short* asrc[8];
  unsigned short* adst[8];
#pragma unroll
  for (int i = 0; i < 8; ++i) {
    int c = t + 384 * i;
    int row = c >> 3;
    int k8 = (c & 7) ^ (row & 7);
    asrc[i] = W + (size_t)row * 256 + k8 * 8;
    adst[i] = &As[w * 512 + i * 3072];
  }
  const bool bst = t < 256;
  size_t bidx[2];
  if (bst) {
#pragma unroll
    for (int i = 0; i < 2; ++i) {
      int c = t + 256 * i;
      int n = c >> 3;
      int bk8 = (c & 7) ^ (n & 7);
      bidx[i] = ((size_t)b * NQ + n0 + n) * 256 + bk8 * 8;
    }
  }

  const int l15 = lane & 15, l4 = lane >> 4;
  facc4 acc[4][4];
#pragma unroll
  for (int i = 0; i < 4; ++i)
#pragma unroll
    for (int j = 0; j < 4; ++j) acc[i][j] = facc4{0.f, 0.f, 0.f, 0.f};

  for (int k0 = 0; k0 < 256; k0 += 64) {
    if (k0) __syncthreads();
#pragma unroll
    for (int i = 0; i < 8; ++i) {
      gload16(asrc[i], adst[i]);
      asrc[i] += 64;
    }
    if (bst) {
#pragma unroll
      for (int i = 0; i < 2; ++i) {
        us8 x = *reinterpret_cast<const us8*>(&S0[bidx[i] + k0]);
        us8 y = *reinterpret_cast<const us8*>(&S1[bidx[i] + k0]);
        us8 o;
#pragma unroll
        for (int j = 0; j < 8; ++j) o[j] = f2bf(bf2f(x[j]) + bf2f(y[j]));
        *reinterpret_cast<us8*>(&Bs[(t + 256 * i) * 8]) = o;
      }
    }
    __syncthreads();
#pragma unroll
    for (int kk = 0; kk < 2; ++kk) {
      bfrag8 af[4], bf[4];
#pragma unroll
      for (int mi = 0; mi < 4; ++mi) {
        int row = w * 64 + mi * 16 + l15;
        af[mi] = *reinterpret_cast<const bfrag8*>(&As[row * 64 + (((kk * 4 + l4) ^ (row & 7)) * 8)]);
      }
#pragma unroll
      for (int ni = 0; ni < 4; ++ni) {
        int row = ni * 16 + l15;
        bf[ni] = *reinterpret_cast<const bfrag8*>(&Bs[row * 64 + (((kk * 4 + l4) ^ (row & 7)) * 8)]);
      }
#pragma unroll
      for (int mi = 0; mi < 4; ++mi)
#pragma unroll
        for (int ni = 0; ni < 4; ++ni)
          acc[mi][ni] = __builtin_amdgcn_mfma_f32_16x16x32_bf16(af[mi], bf[ni], acc[mi][ni], 0, 0, 0);
    }
  }
#pragma unroll
  for (int mi = 0; mi < 4; ++mi) {
    int m = w * 64 + mi * 16 + l4 * 4;
    if (m >= 320) continue;
#pragma unroll
    for (int ni = 0; ni < 4; ++ni) {
      int n = n0 + ni * 16 + l15;
      facc4 v = acc[mi][ni];
#pragma unroll
      for (int r = 0; r < 4; ++r)
        out[((size_t)b * 320 + m + r) * NQ + n] = v[r] + bias[m + r];
    }
  }
}

// ================= deformable bilinear sampling (8192 blocks for TLP) =================
__global__ __launch_bounds__(256) void k_sample(const unsigned short* __restrict__ VP0,
                                                const unsigned short* __restrict__ VP1,
                                                const unsigned short* __restrict__ SWS,
                                                unsigned short* __restrict__ OATT0,
                                                unsigned short* __restrict__ OATT1) {
  int y = blockIdx.y;
  int b = y & 7, br = y >> 3;
  int q0 = blockIdx.x * 8;
  const unsigned short* VP = (br ? VP1 : VP0) + (size_t)b * NQ * 256;
  const unsigned short* SWp = SWS + ((size_t)b * NQ + q0) * 256 + br * 128;
  unsigned short* OATT = (br ? OATT1 : OATT0) + ((size_t)b * NQ + q0) * 256;
  __shared__ unsigned short sws[1024];
  int t = threadIdx.x;
  {
    int row = t >> 5, col = (t & 31) * 4;
    *reinterpret_cast<us4*>(&sws[row * 128 + col]) =
        *reinterpret_cast<const us4*>(&SWp[(size_t)row * 256 + col]);
  }
  __syncthreads();
  int qi = t >> 5, ss = t & 31, head = ss >> 2, hdg = ss & 3;
  int q = q0 + qi;
  const unsigned short* sw = &sws[qi * 128];
  float l0 = bf2f(sw[64 + head * 4 + 0]);
  float l1 = bf2f(sw[64 + head * 4 + 1]);
  float l2 = bf2f(sw[64 + head * 4 + 2]);
  float l3 = bf2f(sw[64 + head * 4 + 3]);
  float mx = fmaxf(fmaxf(l0, l1), fmaxf(l2, l3));
  float e0 = expf(l0 - mx), e1 = expf(l1 - mx), e2 = expf(l2 - mx), e3 = expf(l3 - mx);
  float inv = 1.f / (e0 + e1 + e2 + e3);
  float aw[4] = {e0 * inv, e1 * inv, e2 * inv, e3 * inv};
  float rpx = (float)(q & 63) * (64.f / 63.f) - 0.5f;
  float rpy = (float)(q >> 6) * (64.f / 63.f) - 0.5f;
  const unsigned short* vb = VP + head * 32 + hdg * 8;
  float acc[8] = {};
#pragma unroll
  for (int p = 0; p < 4; ++p) {
    float px = rpx + bf2f(sw[head * 8 + p * 2 + 0]);
    float py = rpy + bf2f(sw[head * 8 + p * 2 + 1]);
    float fx = floorf(px), fy = floorf(py);
    int x0 = (int)fx, y0 = (int)fy;
    float wx = px - fx, wy = py - fy;
#pragma unroll
    for (int dy = 0; dy < 2; ++dy) {
#pragma unroll
      for (int dx = 0; dx < 2; ++dx) {
        int xi = x0 + dx, yi = y0 + dy;
        if (xi >= 0 && xi < 64 && yi >= 0 && yi < 64) {
          float wa = aw[p] * (dx ? wx : 1.f - wx) * (dy ? wy : 1.f - wy);
          bfrag8 v = *reinterpret_cast<const bfrag8*>(&vb[(size_t)(yi * 64 + xi) * 256]);
#pragma unroll
          for (int j = 0; j < 8; ++j) acc[j] = fmaf(wa, bf2f((unsigned short)v[j]), acc[j]);
        }
      }
    }
  }
  us8 o;
#pragma unroll
  for (int j = 0; j < 8; ++j) o[j] = f2bf(acc[j]);
  *reinterpret_cast<us8*>(&OATT[qi * 256 + ss * 8]) = o;
}

extern "C" void kernel_launch(void* const* d_in, const int* in_sizes, int n_in,
                              void* d_out, int out_size, void* d_ws, size_t ws_size,
                              hipStream_t stream) {
  const float* ground = (const float*)d_in[0];
  const float* sat = (const float*)d_in[1];
  const float* osm = (const float*)d_in[2];
  const float* gc_w = (const float*)d_in[3];
  const float* gc_b = (const float*)d_in[4];
  const float* sc_w = (const float*)d_in[5];
  const float* sc_b = (const float*)d_in[6];
  const float* up_w = (const float*)d_in[7];
  const float* up_b = (const float*)d_in[8];
  const float* a_w1 = (const float*)d_in[9];
  const float* a_b1 = (const float*)d_in[10];
  const float* a_w2 = (const float*)d_in[11];
  const float* a_b2 = (const float*)d_in[12];
  const float* vp_w[2] = {(const float*)d_in[13], (const float*)d_in[21]};
  const float* vp_b[2] = {(const float*)d_in[14], (const float*)d_in[22]};
  const float* so_w[2] = {(const float*)d_in[15], (const float*)d_in[23]};
  const float* so_b[2] = {(const float*)d_in[16], (const float*)d_in[24]};
  const float* aw_w[2] = {(const float*)d_in[17], (const float*)d_in[25]};
  const float* aw_b[2] = {(const float*)d_in[18], (const float*)d_in[26]};
  const float* op_w[2] = {(const float*)d_in[19], (const float*)d_in[27]};
  const float* op_b[2] = {(const float*)d_in[20], (const float*)d_in[28]};

  char* wsb = (char*)d_ws;
  const size_t MBy = 1 << 20;
  unsigned short* PET  = (unsigned short*)(wsb);                       // 2 MB
  unsigned short* WG   = (unsigned short*)(wsb + 2 * MBy);             // 512 KB
  unsigned short* WV0  = (unsigned short*)(wsb + 2 * MBy + 524288);    // 160 KB
  unsigned short* WV1  = (unsigned short*)(wsb + 2 * MBy + 786432);    // 160 KB
  unsigned short* WUP  = (unsigned short*)(wsb + 3 * MBy);             // 192 KB
  unsigned short* OPT0 = (unsigned short*)(wsb + 3 * MBy + 262144);    // 128 KB
  unsigned short* OPT1 = (unsigned short*)(wsb + 3 * MBy + 393216);    // 128 KB
  unsigned short* SOWS = (unsigned short*)(wsb + 3 * MBy + 524288);    // 192 KB [384][256]
  unsigned short* PESOS = (unsigned short*)(wsb + 4 * MBy);            // 2 MB [4096][256]
  float* SOBS = (float*)(wsb + 6 * MBy);          // 1 KB
  float* BV0  = (float*)(wsb + 6 * MBy + 4096);
  float* BV1  = (float*)(wsb + 6 * MBy + 8192);
  float* BUPP = (float*)(wsb + 6 * MBy + 12288);
  float* PART = (float*)(wsb + 6 * MBy + 16384);  // 2 KB
  float* AFIN = (float*)(wsb + 6 * MBy + 32768);
  unsigned short* G     = (unsigned short*)(wsb + 8 * MBy);    // 16 MB
  unsigned short* VP0b  = (unsigned short*)(wsb + 24 * MBy);
  unsigned short* VP1b  = (unsigned short*)(wsb + 40 * MBy);
  unsigned short* SWS   = (unsigned short*)(wsb + 56 * MBy);   // [8][4096][256]
  unsigned short* OATT0 = (unsigned short*)(wsb + 72 * MBy);
  unsigned short* OATT1 = (unsigned short*)(wsb + 88 * MBy);
  unsigned short* SATO  = (unsigned short*)(wsb + 104 * MBy);
  unsigned short* OSMO  = (unsigned short*)(wsb + 120 * MBy);

  float* out32 = (float*)d_out;
  float* out_a = out32 + (size_t)NB * 320 * NQ;

  dim3 blk(256);

  // ---- prep ----
  {
    PrepArgs p;
    p.gc_w = gc_w; p.up_w = up_w; p.up_b = up_b;
    p.so_w0 = so_w[0]; p.so_b0 = so_b[0]; p.so_w1 = so_w[1]; p.so_b1 = so_b[1];
    p.aw_w0 = aw_w[0]; p.aw_b0 = aw_b[0]; p.aw_w1 = aw_w[1]; p.aw_b1 = aw_b[1];
    p.a_w1 = a_w1;
    p.op_w0 = op_w[0]; p.op_w1 = op_w[1];
    p.PET = PET; p.WG = WG; p.WUP = WUP;
    p.OPT0 = OPT0; p.OPT1 = OPT1; p.SOWS = SOWS;
    p.BUPP = BUPP; p.SOBS = SOBS;
    mega_prep<<<dim3(6401), blk, 0, stream>>>(p);
  }
  k_wv<<<dim3(16, 2), blk, 0, stream>>>(vp_w[0], vp_b[0], vp_w[1], vp_b[1],
                                        sc_w, sc_b, WV0, WV1, BV0, BV1);

  // ---- PESOS[:, 0:128] = 1*(PE @ SOW0)+b0 ; [:,128:256] = 2*(PE @ SOW1)+b1 ----
  {
    GArgs a = {};
    a.W[0] = SOWS; a.W[1] = SOWS + 128 * 256;
    a.X[0] = PET;  a.X[1] = PET;
    a.bias[0] = SOBS; a.bias[1] = SOBS + 128;
    a.out[0] = PESOS; a.out[1] = PESOS + 128;
    a.rscale[0] = 1.f; a.rscale[1] = 2.f;
    a.K = 256; a.ldm = 256; a.bmask = 0; a.brshift = 0;
    gemm_bf16<1><<<dim3(32, 1, 2), blk, 0, stream>>>(a);
  }

  // ---- gconv: fused transpose from f32 ----
  {
    NArgs a = {};
    a.W[0] = WG; a.W[1] = WG;
    a.X[0] = ground; a.X[1] = ground;
    a.bias[0] = gc_b; a.bias[1] = gc_b;
    a.out[0] = G; a.out[1] = G;
    a.K = 1024; a.zmask = 7; a.zshift = 31;
    gemm_n64<1, 0><<<dim3(64, 1, NB), blk, 0, stream>>>(a);
  }

  // ---- SW (both branches) + alpha hidden, G read once ----
  {
    SAArgs a;
    a.W = SOWS; a.G = G; a.PESOS = PESOS;
    a.b1 = a_b1; a.w2 = a_w2; a.b2 = a_b2;
    a.SWS = SWS; a.partial = PART;
    k_swalpha<<<dim3(64, 1, NB), dim3(384), 0, stream>>>(a);
  }
  k_alpha_fin<<<dim3(NB), dim3(64), 0, stream>>>(PART, AFIN, out_a);

  // ---- VP_br = sat/osm @ WV_br + BV_br (fused transpose from f32) ----
  {
    NArgs a = {};
    a.W[0] = WV0; a.W[1] = WV1;
    a.X[0] = sat; a.X[1] = osm;
    a.bias[0] = BV0; a.bias[1] = BV1;
    a.out[0] = VP0b; a.out[1] = VP1b;
    a.K = 320; a.zmask = 7; a.zshift = 3;
    gemm_n64<1, 0><<<dim3(64, 1, 16), blk, 0, stream>>>(a);
  }

  // ---- sampling (both branches, max TLP) ----
  k_sample<<<dim3(512, 16), blk, 0, stream>>>(VP0b, VP1b, SWS, OATT0, OATT1);

  // ---- dual output proj: SATO = a*(op0+2G+2PE), OSMO = (1-a)*(op1+2G+4PE) ----
  {
    NArgs a = {};
    a.W[0] = OPT0; a.W[1] = OPT1;
    a.X[0] = OATT0; a.X[1] = OATT1;
    a.bias[0] = op_b[0]; a.bias[1] = op_b[1];
    a.out[0] = SATO; a.out[1] = OSMO;
    a.G = G; a.PET = PET; a.afin = AFIN;
    a.rs[0] = 2.f; a.rs[1] = 4.f;
    a.K = 256; a.zmask = 7; a.zshift = 3;
    gemm_n64<0, 6><<<dim3(64, 1, 16), blk, 0, stream>>>(a);
  }

  // ---- up conv: B = SATO+OSMO blended in staging, f32 out ----
  gemm_up<<<dim3(64, 1, NB), dim3(384), 0, stream>>>(WUP, SATO, OSMO, BUPP, out32);
}

// Round 10
// 244.196 us; speedup vs baseline: 1.5787x; 1.1144x over previous
//
#include <hip/hip_runtime.h>
#include <cstddef>
#include <cstdint>

#define NB 8
#define NQ 4096

typedef __attribute__((ext_vector_type(8))) short bfrag8;
typedef __attribute__((ext_vector_type(4))) float facc4;
typedef __attribute__((ext_vector_type(4))) unsigned short us4;
typedef __attribute__((ext_vector_type(8))) unsigned short us8;

__device__ __forceinline__ float bf2f(unsigned short u) {
  union { unsigned int i; float f; } v; v.i = ((unsigned int)u) << 16; return v.f;
}
__device__ __forceinline__ unsigned short f2bf(float f) {
  union { float f; unsigned int i; } v; v.f = f;
  unsigned int r = v.i + 0x7FFFu + ((v.i >> 16) & 1u);
  return (unsigned short)(r >> 16);
}
__device__ __forceinline__ void gload16(const void* g, void* l) {
  __builtin_amdgcn_global_load_lds(
      (const __attribute__((address_space(1))) void*)g,
      (__attribute__((address_space(3))) void*)l, 16, 0, 0);
}

// ================= mega prep: weight conversions + k_wv tail =================
struct PrepArgs {
  const float *gc_w, *up_w, *up_b;
  const float *so_w0, *so_b0, *so_w1, *so_b1;
  const float *aw_w0, *aw_b0, *aw_w1, *aw_b1;
  const float *a_w1;
  const float *op_w0, *op_w1;
  const float *vp_w0, *vp_b0, *vp_w1, *vp_b1, *sc_w, *sc_b;
  unsigned short *PET, *WG, *WUP, *OPT0, *OPT1, *SOWS, *WV0, *WV1;
  float *BUPP, *SOBS, *BV0, *BV1;
};

__global__ __launch_bounds__(256) void mega_prep(PrepArgs p) {
  __shared__ float vt[32][256];
  __shared__ float st[32][20];
  __shared__ float sb[32];
  const int blk = blockIdx.x, t = threadIdx.x;
  if (blk < 4096) {
    int idx = blk * 256 + t;
    int q = idx >> 8, c = idx & 255;
    int h = q >> 6, w = q & 63;
    int k = c >> 2, m = c & 3;
    float dv = expf((float)(2 * k) * (-9.210340371976184f / 128.0f));
    float arg = ((m < 2) ? (float)w : (float)h) * dv;
    p.PET[idx] = f2bf(((m & 1) == 0) ? sinf(arg) : cosf(arg));
  } else if (blk < 5120) {
    int i = (blk - 4096) * 256 + t;
    p.WG[i] = f2bf(p.gc_w[i]);
  } else if (blk < 5504) {
    int i = (blk - 5120) * 256 + t;
    int m = i >> 8, k = i & 255;
    p.WUP[i] = (m < 320) ? f2bf(p.up_w[m * 256 + k]) : 0;
  } else if (blk < 5505) {
    p.BUPP[t] = (t < 320) ? p.up_b[t] : 0.f;
    if (t < 128) {
      int i2 = 256 + t;
      p.BUPP[i2] = (i2 < 320) ? p.up_b[i2] : 0.f;
    }
  } else if (blk < 6017) {
    int i = (blk - 5505) * 256 + t;
    int which = i >> 16, j = i & 65535;
    int o = j >> 8, k = j & 255;
    (which ? p.OPT1 : p.OPT0)[j] = f2bf((which ? p.op_w1 : p.op_w0)[k * 256 + o]);
  } else if (blk < 6401) {
    // SOWS [384][256]: rows 0-127 br0 (so|aw|pad), 128-255 br1, 256-319 a_w1^T, 320-383 zero
    int i = (blk - 6017) * 256 + t;
    int row = i >> 8, k = i & 255;
    float v = 0.f;
    if (row < 256) {
      int br = row >> 7, rr = row & 127;
      const float* sw = br ? p.so_w1 : p.so_w0;
      const float* aw = br ? p.aw_w1 : p.aw_w0;
      if (rr < 64) v = sw[k * 64 + rr];
      else if (rr < 96) v = aw[k * 32 + (rr - 64)];
    } else if (row < 320) {
      v = p.a_w1[k * 64 + (row - 256)];
    }
    p.SOWS[i] = f2bf(v);
    if (i < 256) {
      int br = i >> 7, rr = i & 127;
      const float* sbp = br ? p.so_b1 : p.so_b0;
      const float* abp = br ? p.aw_b1 : p.aw_b0;
      p.SOBS[i] = (rr < 64) ? sbp[rr] : ((rr < 96) ? abp[rr - 64] : 0.f);
    }
  } else {
    // k_wv: WV[br][m][k] = sum_c vp[c][m]*sc_w[c][k] ; BV[br][m]
    int bi = blk - 6401;
    int kt = bi & 15, br = bi >> 4, k0 = kt * 20;
    const float* vp = br ? p.vp_w1 : p.vp_w0;
    unsigned short* WV = br ? p.WV1 : p.WV0;
    float acc[20] = {};
    float accB = 0.f;
    for (int c0 = 0; c0 < 256; c0 += 32) {
      __syncthreads();
#pragma unroll
      for (int cc = 0; cc < 32; ++cc)
        vt[cc][t] = vp[(size_t)(c0 + cc) * 256 + t];
      for (int i = t; i < 640; i += 256)
        st[i / 20][i % 20] = p.sc_w[(size_t)(c0 + i / 20) * 320 + k0 + (i % 20)];
      if (t < 32) sb[t] = p.sc_b[c0 + t];
      __syncthreads();
#pragma unroll
      for (int cc = 0; cc < 32; ++cc) {
        float v = vt[cc][t];
        accB = fmaf(v, sb[cc], accB);
#pragma unroll
        for (int j = 0; j < 20; ++j)
          acc[j] = fmaf(v, st[cc][j], acc[j]);
      }
    }
#pragma unroll
    for (int j = 0; j < 20; ++j) WV[(size_t)t * 320 + k0 + j] = f2bf(acc[j]);
    if (kt == 0) (br ? p.BV1 : p.BV0)[t] = (br ? p.vp_b1 : p.vp_b0)[t] + accB;
  }
}

// ================= mega GEMM: gconv + VPsat + VPosm + PESOS in one dispatch =================
// routes: z0-7 gconv (K=1024, f32 X) ; z8-15 VPsat (K=320, f32) ; z16-23 VPosm (K=320, f32)
//         z24 PESOS (K=256, bf16 X=PET, rscale = m<128?1:2)
struct MArgs {
  const unsigned short* W[4];
  const void* X[4];
  const float* bias[4];
  void* out[4];
  int K[4];
};
__global__ __launch_bounds__(256) void gemm_mega(MArgs g) {
  __shared__ unsigned short As[16384]; // [256][64] swizzled
  __shared__ unsigned short Bs[4096];  // [64][64] swizzled
  const int t = threadIdx.x;
  const int lane = t & 63, w = t >> 6;
  const int z = blockIdx.z;
  int route, b;
  if (z < 8) { route = 0; b = z; }
  else if (z < 16) { route = 1; b = z - 8; }
  else if (z < 24) { route = 2; b = z - 16; }
  else { route = 3; b = 0; }
  const int K = g.K[route];
  const int n0 = blockIdx.x * 64;

  const unsigned short* W = g.W[route];
  const unsigned short* asrc[8];
  unsigned short* adst[8];
#pragma unroll
  for (int i = 0; i < 8; ++i) {
    int c = t + 256 * i;
    int row = c >> 3;
    int k8 = (c & 7) ^ (row & 7);
    asrc[i] = W + (size_t)row * K + k8 * 8;
    adst[i] = &As[w * 512 + i * 2048];
  }

  const unsigned short* bsrc16[2];
  unsigned short* bdst16[2];
  const float* bsrcf = nullptr;
  const int kb = t >> 4, nb = t & 15;
  if (route == 3) {
    const unsigned short* Xh = (const unsigned short*)g.X[3];
#pragma unroll
    for (int i = 0; i < 2; ++i) {
      int c = t + 256 * i;
      int n = c >> 3;
      int k8 = (c & 7) ^ (n & 7);
      bsrc16[i] = Xh + (size_t)(n0 + n) * K + k8 * 8;
      bdst16[i] = &Bs[w * 512 + i * 2048];
    }
  } else {
    const float* Xf = (const float*)g.X[route];
    bsrcf = Xf + (size_t)b * K * NQ + (size_t)(kb * 4) * NQ + n0 + nb * 4;
  }

  const int l15 = lane & 15, l4 = lane >> 4;
  facc4 acc[4][4];
#pragma unroll
  for (int i = 0; i < 4; ++i)
#pragma unroll
    for (int j = 0; j < 4; ++j) acc[i][j] = facc4{0.f, 0.f, 0.f, 0.f};

  for (int k0 = 0; k0 < K; k0 += 64) {
    if (k0) __syncthreads();
#pragma unroll
    for (int i = 0; i < 8; ++i) {
      gload16(asrc[i], adst[i]);
      asrc[i] += 64;
    }
    if (route == 3) {
      gload16(bsrc16[0], bdst16[0]); bsrc16[0] += 64;
      gload16(bsrc16[1], bdst16[1]); bsrc16[1] += 64;
    } else {
      float vv[4][4];
#pragma unroll
      for (int r = 0; r < 4; ++r) {
        float4 v = *reinterpret_cast<const float4*>(bsrcf + (size_t)k0 * NQ + (size_t)r * NQ);
        vv[r][0] = v.x; vv[r][1] = v.y; vv[r][2] = v.z; vv[r][3] = v.w;
      }
#pragma unroll
      for (int c = 0; c < 4; ++c) {
        int n = nb * 4 + c;
        us4 pk;
        pk[0] = f2bf(vv[0][c]); pk[1] = f2bf(vv[1][c]);
        pk[2] = f2bf(vv[2][c]); pk[3] = f2bf(vv[3][c]);
        int off = n * 64 + (((kb >> 1) ^ (n & 7)) * 8) + (kb & 1) * 4;
        *reinterpret_cast<us4*>(&Bs[off]) = pk;
      }
    }
    __syncthreads();
#pragma unroll
    for (int kk = 0; kk < 2; ++kk) {
      bfrag8 af[4], bf[4];
#pragma unroll
      for (int mi = 0; mi < 4; ++mi) {
        int row = w * 64 + mi * 16 + l15;
        af[mi] = *reinterpret_cast<const bfrag8*>(&As[row * 64 + (((kk * 4 + l4) ^ (row & 7)) * 8)]);
      }
#pragma unroll
      for (int ni = 0; ni < 4; ++ni) {
        int row = ni * 16 + l15;
        bf[ni] = *reinterpret_cast<const bfrag8*>(&Bs[row * 64 + (((kk * 4 + l4) ^ (row & 7)) * 8)]);
      }
#pragma unroll
      for (int mi = 0; mi < 4; ++mi)
#pragma unroll
        for (int ni = 0; ni < 4; ++ni)
          acc[mi][ni] = __builtin_amdgcn_mfma_f32_16x16x32_bf16(af[mi], bf[ni], acc[mi][ni], 0, 0, 0);
    }
  }

  const size_t bq = (size_t)b * NQ;
  unsigned short* o16 = (unsigned short*)g.out[route];
  const float* bias = g.bias[route];
#pragma unroll
  for (int mi = 0; mi < 4; ++mi) {
#pragma unroll
    for (int ni = 0; ni < 4; ++ni) {
      int m = w * 64 + mi * 16 + l4 * 4;
      int n = n0 + ni * 16 + l15;
      facc4 v = acc[mi][ni];
      float sc = (route == 3 && m >= 128) ? 2.f : 1.f;
      float4 bv = *reinterpret_cast<const float4*>(&bias[m]);
      us4 pk;
      pk[0] = f2bf(v[0] * sc + bv.x); pk[1] = f2bf(v[1] * sc + bv.y);
      pk[2] = f2bf(v[2] * sc + bv.z); pk[3] = f2bf(v[3] * sc + bv.w);
      *reinterpret_cast<us4*>(&o16[(bq + n) * 256 + m]) = pk;
    }
  }
}

// ================= SW + alpha fused: M=384 (SW0|SW1|alpha-hidden), B=G =================
struct SAArgs {
  const unsigned short *W;      // SOWS [384][256]
  const unsigned short *G;
  const unsigned short *PESOS;  // [4096][256]
  const float *b1, *w2, *b2;
  unsigned short *SWS;          // [8][4096][256]
  float *partial;               // [8][64]
};
__global__ __launch_bounds__(384) void k_swalpha(SAArgs g) {
  __shared__ unsigned short As[24576];
  __shared__ unsigned short Bs[4096];
  const int t = threadIdx.x;
  const int lane = t & 63, w = t >> 6;
  const int b = blockIdx.z;
  const int n0 = blockIdx.x * 64;

  const unsigned short* asrc[8];
  unsigned short* adst[8];
#pragma unroll
  for (int i = 0; i < 8; ++i) {
    int c = t + 384 * i;
    int row = c >> 3;
    int k8 = (c & 7) ^ (row & 7);
    asrc[i] = g.W + (size_t)row * 256 + k8 * 8;
    adst[i] = &As[w * 512 + i * 3072];
  }
  const bool bst = t < 256;
  const unsigned short* bsrc[2];
  unsigned short* bdst[2];
  if (bst) {
#pragma unroll
    for (int i = 0; i < 2; ++i) {
      int c = t + 256 * i;
      int n = c >> 3;
      int k8 = (c & 7) ^ (n & 7);
      bsrc[i] = g.G + ((size_t)b * NQ + n0 + n) * 256 + k8 * 8;
      bdst[i] = &Bs[w * 512 + i * 2048];
    }
  }

  const int l15 = lane & 15, l4 = lane >> 4;
  facc4 acc[4][4];
#pragma unroll
  for (int i = 0; i < 4; ++i)
#pragma unroll
    for (int j = 0; j < 4; ++j) acc[i][j] = facc4{0.f, 0.f, 0.f, 0.f};

  for (int k0 = 0; k0 < 256; k0 += 64) {
    if (k0) __syncthreads();
#pragma unroll
    for (int i = 0; i < 8; ++i) {
      gload16(asrc[i], adst[i]);
      asrc[i] += 64;
    }
    if (bst) {
      gload16(bsrc[0], bdst[0]); bsrc[0] += 64;
      gload16(bsrc[1], bdst[1]); bsrc[1] += 64;
    }
    __syncthreads();
    if (w < 5) {
#pragma unroll
      for (int kk = 0; kk < 2; ++kk) {
        bfrag8 af[4], bf[4];
#pragma unroll
        for (int mi = 0; mi < 4; ++mi) {
          int row = w * 64 + mi * 16 + l15;
          af[mi] = *reinterpret_cast<const bfrag8*>(&As[row * 64 + (((kk * 4 + l4) ^ (row & 7)) * 8)]);
        }
#pragma unroll
        for (int ni = 0; ni < 4; ++ni) {
          int row = ni * 16 + l15;
          bf[ni] = *reinterpret_cast<const bfrag8*>(&Bs[row * 64 + (((kk * 4 + l4) ^ (row & 7)) * 8)]);
        }
#pragma unroll
        for (int mi = 0; mi < 4; ++mi)
#pragma unroll
          for (int ni = 0; ni < 4; ++ni)
            acc[mi][ni] = __builtin_amdgcn_mfma_f32_16x16x32_bf16(af[mi], bf[ni], acc[mi][ni], 0, 0, 0);
      }
    }
  }

  const size_t bq = (size_t)b * NQ;
  if (w < 4) {
#pragma unroll
    for (int mi = 0; mi < 4; ++mi) {
#pragma unroll
      for (int ni = 0; ni < 4; ++ni) {
        int m = w * 64 + mi * 16 + l4 * 4;
        int n = n0 + ni * 16 + l15;
        facc4 v = acc[mi][ni];
        us4 rr = *reinterpret_cast<const us4*>(&g.PESOS[(size_t)n * 256 + m]);
        us4 pk;
#pragma unroll
        for (int r = 0; r < 4; ++r) pk[r] = f2bf(v[r] + bf2f(rr[r]));
        *reinterpret_cast<us4*>(&g.SWS[(bq + n) * 256 + m]) = pk;
      }
    }
  } else if (w == 4) {
    float b2v = g.b2[0];
    float ssum = 0.f;
#pragma unroll
    for (int ni = 0; ni < 4; ++ni) {
      float s = 0.f;
#pragma unroll
      for (int mi = 0; mi < 4; ++mi) {
#pragma unroll
        for (int r = 0; r < 4; ++r) {
          int hid = mi * 16 + l4 * 4 + r;
          s += fmaxf(acc[mi][ni][r] + g.b1[hid], 0.f) * g.w2[hid];
        }
      }
      s += __shfl_xor(s, 16);
      s += __shfl_xor(s, 32);
      ssum += 1.f / (1.f + expf(-(s + b2v)));
    }
    ssum += __shfl_xor(ssum, 1);
    ssum += __shfl_xor(ssum, 2);
    ssum += __shfl_xor(ssum, 4);
    ssum += __shfl_xor(ssum, 8);
    if (lane == 0) g.partial[b * 64 + blockIdx.x] = ssum;
  }
}

// ================= deformable bilinear sampling (8192 blocks for TLP) =================
__global__ __launch_bounds__(256) void k_sample(const unsigned short* __restrict__ VP0,
                                                const unsigned short* __restrict__ VP1,
                                                const unsigned short* __restrict__ SWS,
                                                unsigned short* __restrict__ OATT0,
                                                unsigned short* __restrict__ OATT1) {
  int y = blockIdx.y;
  int b = y & 7, br = y >> 3;
  int q0 = blockIdx.x * 8;
  const unsigned short* VP = (br ? VP1 : VP0) + (size_t)b * NQ * 256;
  const unsigned short* SWp = SWS + ((size_t)b * NQ + q0) * 256 + br * 128;
  unsigned short* OATT = (br ? OATT1 : OATT0) + ((size_t)b * NQ + q0) * 256;
  __shared__ unsigned short sws[1024];
  int t = threadIdx.x;
  {
    int row = t >> 5, col = (t & 31) * 4;
    *reinterpret_cast<us4*>(&sws[row * 128 + col]) =
        *reinterpret_cast<const us4*>(&SWp[(size_t)row * 256 + col]);
  }
  __syncthreads();
  int qi = t >> 5, ss = t & 31, head = ss >> 2, hdg = ss & 3;
  int q = q0 + qi;
  const unsigned short* sw = &sws[qi * 128];
  float l0 = bf2f(sw[64 + head * 4 + 0]);
  float l1 = bf2f(sw[64 + head * 4 + 1]);
  float l2 = bf2f(sw[64 + head * 4 + 2]);
  float l3 = bf2f(sw[64 + head * 4 + 3]);
  float mx = fmaxf(fmaxf(l0, l1), fmaxf(l2, l3));
  float e0 = expf(l0 - mx), e1 = expf(l1 - mx), e2 = expf(l2 - mx), e3 = expf(l3 - mx);
  float inv = 1.f / (e0 + e1 + e2 + e3);
  float aw[4] = {e0 * inv, e1 * inv, e2 * inv, e3 * inv};
  float rpx = (float)(q & 63) * (64.f / 63.f) - 0.5f;
  float rpy = (float)(q >> 6) * (64.f / 63.f) - 0.5f;
  const unsigned short* vb = VP + head * 32 + hdg * 8;
  float acc[8] = {};
#pragma unroll
  for (int p = 0; p < 4; ++p) {
    float px = rpx + bf2f(sw[head * 8 + p * 2 + 0]);
    float py = rpy + bf2f(sw[head * 8 + p * 2 + 1]);
    float fx = floorf(px), fy = floorf(py);
    int x0 = (int)fx, y0 = (int)fy;
    float wx = px - fx, wy = py - fy;
#pragma unroll
    for (int dy = 0; dy < 2; ++dy) {
#pragma unroll
      for (int dx = 0; dx < 2; ++dx) {
        int xi = x0 + dx, yi = y0 + dy;
        if (xi >= 0 && xi < 64 && yi >= 0 && yi < 64) {
          float wa = aw[p] * (dx ? wx : 1.f - wx) * (dy ? wy : 1.f - wy);
          bfrag8 v = *reinterpret_cast<const bfrag8*>(&vb[(size_t)(yi * 64 + xi) * 256]);
#pragma unroll
          for (int j = 0; j < 8; ++j) acc[j] = fmaf(wa, bf2f((unsigned short)v[j]), acc[j]);
        }
      }
    }
  }
  us8 o;
#pragma unroll
  for (int j = 0; j < 8; ++j) o[j] = f2bf(acc[j]);
  *reinterpret_cast<us8*>(&OATT[qi * 256 + ss * 8]) = o;
}

// ================= fused dual op-proj + blend + up-conv =================
struct UArgs {
  const unsigned short *OATT0, *OATT1, *OPT0, *OPT1, *G, *PET, *WUP;
  const float *opb0, *opb1, *BUPP, *PART;
  float *out, *out_a;
};
__global__ __launch_bounds__(256) void k_opup(UArgs g) {
  __shared__ unsigned short As[20480]; // ph1: [256][64] (32KB); ph2: [320][64] (40KB)
  __shared__ unsigned short Bs[4096];  // [64][64]
  __shared__ unsigned short P[16384];  // [64 n][256 ch] swizzled, bf16 blended
  const int t = threadIdx.x;
  const int lane = t & 63, w = t >> 6;
  const int b = blockIdx.y;
  const int n0 = blockIdx.x * 64;
  const int l15 = lane & 15, l4 = lane >> 4;
  const size_t bq = (size_t)b * NQ;

  // alpha from PART (redundant per block, deterministic)
  float av = g.PART[b * 64 + lane];
#pragma unroll
  for (int off = 1; off < 64; off <<= 1) av += __shfl_xor(av, off);
  const float a = av * (1.f / 4096.f);
  if (blockIdx.x == 0 && t == 0) g.out_a[b] = a;

  // ---------- phase 1: per-branch op-proj -> blended P ----------
  for (int br = 0; br < 2; ++br) {
    const unsigned short* OPT = br ? g.OPT1 : g.OPT0;
    const unsigned short* OATT = (br ? g.OATT1 : g.OATT0) + bq * 256;
    const float* opb = br ? g.opb1 : g.opb0;
    facc4 acc[4][4];
#pragma unroll
    for (int i = 0; i < 4; ++i)
#pragma unroll
      for (int j = 0; j < 4; ++j) acc[i][j] = facc4{0.f, 0.f, 0.f, 0.f};

    for (int kt = 0; kt < 4; ++kt) {
      __syncthreads();
#pragma unroll
      for (int i = 0; i < 8; ++i) {
        int c = t + 256 * i;
        int row = c >> 3;
        int k8 = (c & 7) ^ (row & 7);
        gload16(OPT + (size_t)row * 256 + kt * 64 + k8 * 8, &As[w * 512 + i * 2048]);
      }
#pragma unroll
      for (int i = 0; i < 2; ++i) {
        int c = t + 256 * i;
        int n = c >> 3;
        int k8 = (c & 7) ^ (n & 7);
        gload16(OATT + (size_t)(n0 + n) * 256 + kt * 64 + k8 * 8, &Bs[w * 512 + i * 2048]);
      }
      __syncthreads();
#pragma unroll
      for (int kk = 0; kk < 2; ++kk) {
        bfrag8 af[4], bf[4];
#pragma unroll
        for (int mi = 0; mi < 4; ++mi) {
          int row = w * 64 + mi * 16 + l15;
          af[mi] = *reinterpret_cast<const bfrag8*>(&As[row * 64 + (((kk * 4 + l4) ^ (row & 7)) * 8)]);
        }
#pragma unroll
        for (int ni = 0; ni < 4; ++ni) {
          int row = ni * 16 + l15;
          bf[ni] = *reinterpret_cast<const bfrag8*>(&Bs[row * 64 + (((kk * 4 + l4) ^ (row & 7)) * 8)]);
        }
#pragma unroll
        for (int mi = 0; mi < 4; ++mi)
#pragma unroll
          for (int ni = 0; ni < 4; ++ni)
            acc[mi][ni] = __builtin_amdgcn_mfma_f32_16x16x32_bf16(af[mi], bf[ni], acc[mi][ni], 0, 0, 0);
      }
    }
    // epilogue: rv = acc + opb + 2*G + rs*PE ; blend into P (same thread owns both passes)
    const float rs = br ? 4.f : 2.f;
    const float s = br ? (1.f - a) : a;
#pragma unroll
    for (int mi = 0; mi < 4; ++mi) {
#pragma unroll
      for (int ni = 0; ni < 4; ++ni) {
        int m = w * 64 + mi * 16 + l4 * 4;
        int nloc = ni * 16 + l15;
        int n = n0 + nloc;
        float4 bv = *reinterpret_cast<const float4*>(&opb[m]);
        us4 gv = *reinterpret_cast<const us4*>(&g.G[(bq + n) * 256 + m]);
        us4 pv = *reinterpret_cast<const us4*>(&g.PET[(size_t)n * 256 + m]);
        facc4 v = acc[mi][ni];
        float bb[4] = {bv.x, bv.y, bv.z, bv.w};
        int pidx = nloc * 256 + (m >> 6) * 64 + ((((m >> 3) & 7) ^ (nloc & 7)) * 8) + (m & 7);
        us4 pk;
        if (br == 0) {
#pragma unroll
          for (int r = 0; r < 4; ++r)
            pk[r] = f2bf(s * (v[r] + bb[r] + 2.f * bf2f(gv[r]) + rs * bf2f(pv[r])));
        } else {
          us4 old = *reinterpret_cast<const us4*>(&P[pidx]);
#pragma unroll
          for (int r = 0; r < 4; ++r)
            pk[r] = f2bf(bf2f(old[r]) + s * (v[r] + bb[r] + 2.f * bf2f(gv[r]) + rs * bf2f(pv[r])));
        }
        *reinterpret_cast<us4*>(&P[pidx]) = pk;
      }
    }
  }
  __syncthreads();

  // ---------- phase 2: up-conv, B = P from LDS ----------
  facc4 au[5][4];
#pragma unroll
  for (int i = 0; i < 5; ++i)
#pragma unroll
    for (int j = 0; j < 4; ++j) au[i][j] = facc4{0.f, 0.f, 0.f, 0.f};

  for (int kt = 0; kt < 4; ++kt) {
    __syncthreads();
#pragma unroll
    for (int i = 0; i < 10; ++i) {
      int c = t + 256 * i;
      int row = c >> 3;
      int k8 = (c & 7) ^ (row & 7);
      gload16(g.WUP + (size_t)row * 256 + kt * 64 + k8 * 8, &As[w * 512 + i * 2048]);
    }
    __syncthreads();
#pragma unroll
    for (int kk = 0; kk < 2; ++kk) {
      bfrag8 bf[4];
#pragma unroll
      for (int ni = 0; ni < 4; ++ni) {
        int n = ni * 16 + l15;
        bf[ni] = *reinterpret_cast<const bfrag8*>(&P[n * 256 + kt * 64 + (((kk * 4 + l4) ^ (n & 7)) * 8)]);
      }
#pragma unroll
      for (int j = 0; j < 5; ++j) {
        int row = (w * 5 + j) * 16 + l15;
        bfrag8 af = *reinterpret_cast<const bfrag8*>(&As[row * 64 + (((kk * 4 + l4) ^ (row & 7)) * 8)]);
#pragma unroll
        for (int ni = 0; ni < 4; ++ni)
          au[j][ni] = __builtin_amdgcn_mfma_f32_16x16x32_bf16(af, bf[ni], au[j][ni], 0, 0, 0);
      }
    }
  }
#pragma unroll
  for (int j = 0; j < 5; ++j) {
    int m = (w * 5 + j) * 16 + l4 * 4;
#pragma unroll
    for (int ni = 0; ni < 4; ++ni) {
      int n = n0 + ni * 16 + l15;
      facc4 v = au[j][ni];
#pragma unroll
      for (int r = 0; r < 4; ++r)
        g.out[((size_t)b * 320 + m + r) * NQ + n] = v[r] + g.BUPP[m + r];
    }
  }
}

extern "C" void kernel_launch(void* const* d_in, const int* in_sizes, int n_in,
                              void* d_out, int out_size, void* d_ws, size_t ws_size,
                              hipStream_t stream) {
  const float* ground = (const float*)d_in[0];
  const float* sat = (const float*)d_in[1];
  const float* osm = (const float*)d_in[2];
  const float* gc_w = (const float*)d_in[3];
  const float* gc_b = (const float*)d_in[4];
  const float* sc_w = (const float*)d_in[5];
  const float* sc_b = (const float*)d_in[6];
  const float* up_w = (const float*)d_in[7];
  const float* up_b = (const float*)d_in[8];
  const float* a_w1 = (const float*)d_in[9];
  const float* a_b1 = (const float*)d_in[10];
  const float* a_w2 = (const float*)d_in[11];
  const float* a_b2 = (const float*)d_in[12];
  const float* vp_w[2] = {(const float*)d_in[13], (const float*)d_in[21]};
  const float* vp_b[2] = {(const float*)d_in[14], (const float*)d_in[22]};
  const float* so_w[2] = {(const float*)d_in[15], (const float*)d_in[23]};
  const float* so_b[2] = {(const float*)d_in[16], (const float*)d_in[24]};
  const float* aw_w[2] = {(const float*)d_in[17], (const float*)d_in[25]};
  const float* aw_b[2] = {(const float*)d_in[18], (const float*)d_in[26]};
  const float* op_w[2] = {(const float*)d_in[19], (const float*)d_in[27]};
  const float* op_b[2] = {(const float*)d_in[20], (const float*)d_in[28]};

  char* wsb = (char*)d_ws;
  const size_t MBy = 1 << 20;
  unsigned short* PET  = (unsigned short*)(wsb);                       // 2 MB
  unsigned short* WG   = (unsigned short*)(wsb + 2 * MBy);             // 512 KB
  unsigned short* WV0  = (unsigned short*)(wsb + 2 * MBy + 524288);    // 160 KB
  unsigned short* WV1  = (unsigned short*)(wsb + 2 * MBy + 786432);    // 160 KB
  unsigned short* WUP  = (unsigned short*)(wsb + 3 * MBy);             // 192 KB
  unsigned short* OPT0 = (unsigned short*)(wsb + 3 * MBy + 262144);    // 128 KB
  unsigned short* OPT1 = (unsigned short*)(wsb + 3 * MBy + 393216);    // 128 KB
  unsigned short* SOWS = (unsigned short*)(wsb + 3 * MBy + 524288);    // 192 KB [384][256]
  unsigned short* PESOS = (unsigned short*)(wsb + 4 * MBy);            // 2 MB [4096][256]
  float* SOBS = (float*)(wsb + 6 * MBy);
  float* BV0  = (float*)(wsb + 6 * MBy + 4096);
  float* BV1  = (float*)(wsb + 6 * MBy + 8192);
  float* BUPP = (float*)(wsb + 6 * MBy + 12288);
  float* PART = (float*)(wsb + 6 * MBy + 16384);
  unsigned short* G     = (unsigned short*)(wsb + 8 * MBy);    // 16 MB
  unsigned short* VP0b  = (unsigned short*)(wsb + 24 * MBy);
  unsigned short* VP1b  = (unsigned short*)(wsb + 40 * MBy);
  unsigned short* SWS   = (unsigned short*)(wsb + 56 * MBy);
  unsigned short* OATT0 = (unsigned short*)(wsb + 72 * MBy);
  unsigned short* OATT1 = (unsigned short*)(wsb + 88 * MBy);

  float* out32 = (float*)d_out;
  float* out_a = out32 + (size_t)NB * 320 * NQ;

  dim3 blk(256);

  // ---- prep (weight converts + WV/BV tail blocks) ----
  {
    PrepArgs p;
    p.gc_w = gc_w; p.up_w = up_w; p.up_b = up_b;
    p.so_w0 = so_w[0]; p.so_b0 = so_b[0]; p.so_w1 = so_w[1]; p.so_b1 = so_b[1];
    p.aw_w0 = aw_w[0]; p.aw_b0 = aw_b[0]; p.aw_w1 = aw_w[1]; p.aw_b1 = aw_b[1];
    p.a_w1 = a_w1;
    p.op_w0 = op_w[0]; p.op_w1 = op_w[1];
    p.vp_w0 = vp_w[0]; p.vp_b0 = vp_b[0]; p.vp_w1 = vp_w[1]; p.vp_b1 = vp_b[1];
    p.sc_w = sc_w; p.sc_b = sc_b;
    p.PET = PET; p.WG = WG; p.WUP = WUP;
    p.OPT0 = OPT0; p.OPT1 = OPT1; p.SOWS = SOWS; p.WV0 = WV0; p.WV1 = WV1;
    p.BUPP = BUPP; p.SOBS = SOBS; p.BV0 = BV0; p.BV1 = BV1;
    mega_prep<<<dim3(6433), blk, 0, stream>>>(p);
  }

  // ---- mega GEMM: gconv + VPsat + VPosm + PESOS concurrently ----
  {
    MArgs a;
    a.W[0] = WG;    a.X[0] = ground; a.bias[0] = gc_b; a.out[0] = G;     a.K[0] = 1024;
    a.W[1] = WV0;   a.X[1] = sat;    a.bias[1] = BV0;  a.out[1] = VP0b;  a.K[1] = 320;
    a.W[2] = WV1;   a.X[2] = osm;    a.bias[2] = BV1;  a.out[2] = VP1b;  a.K[2] = 320;
    a.W[3] = SOWS;  a.X[3] = PET;    a.bias[3] = SOBS; a.out[3] = PESOS; a.K[3] = 256;
    gemm_mega<<<dim3(64, 1, 25), blk, 0, stream>>>(a);
  }

  // ---- SW (both branches) + alpha hidden, G read once ----
  {
    SAArgs a;
    a.W = SOWS; a.G = G; a.PESOS = PESOS;
    a.b1 = a_b1; a.w2 = a_w2; a.b2 = a_b2;
    a.SWS = SWS; a.partial = PART;
    k_swalpha<<<dim3(64, 1, NB), dim3(384), 0, stream>>>(a);
  }

  // ---- sampling (both branches, max TLP) ----
  k_sample<<<dim3(512, 16), blk, 0, stream>>>(VP0b, VP1b, SWS, OATT0, OATT1);

  // ---- fused dual op-proj + blend + up-conv -> f32 out ----
  {
    UArgs a;
    a.OATT0 = OATT0; a.OATT1 = OATT1;
    a.OPT0 = OPT0; a.OPT1 = OPT1;
    a.G = G; a.PET = PET; a.WUP = WUP;
    a.opb0 = op_b[0]; a.opb1 = op_b[1];
    a.BUPP = BUPP; a.PART = PART;
    a.out = out32; a.out_a = out_a;
    k_opup<<<dim3(64, NB), blk, 0, stream>>>(a);
  }
}